// Round 1
// baseline (1142.428 us; speedup 1.0000x reference)
//
#include <hip/hip_runtime.h>

#define NH 24
#define HD 128
#define DM 3072
#define DM3 9216
#define STXT 256
#define SIMG 2048
#define SALL 2304

typedef __attribute__((ext_vector_type(8))) short bfrag;
typedef __attribute__((ext_vector_type(4))) float ffrag;

__device__ __forceinline__ unsigned short f2bf(float f) {
  unsigned int x = __builtin_bit_cast(unsigned int, f);
  x += 0x7fffu + ((x >> 16) & 1u);
  return (unsigned short)(x >> 16);
}

// async 16B global->LDS (DMA, no VGPR round-trip). LDS dest must be linear
// (wave-uniform base + lane*16); swizzled layouts via pre-permuted global src.
__device__ __forceinline__ void gload16(void* lds, const void* g) {
  __builtin_amdgcn_global_load_lds((const __attribute__((address_space(1))) unsigned int*)g,
                                   (__attribute__((address_space(3))) unsigned int*)lds, 16, 0, 0);
}

// ---------------- cast fp32 -> bf16 (8 elems/thread) ----------------
__global__ __launch_bounds__(256) void cast_kernel(const float* __restrict__ in,
                                                   unsigned short* __restrict__ out) {
  int i = blockIdx.x * 256 + threadIdx.x;
  float4 a = ((const float4*)in)[2 * i];
  float4 b = ((const float4*)in)[2 * i + 1];
  uint4 o;
  o.x = (unsigned)f2bf(a.x) | ((unsigned)f2bf(a.y) << 16);
  o.y = (unsigned)f2bf(a.z) | ((unsigned)f2bf(a.w) << 16);
  o.z = (unsigned)f2bf(b.x) | ((unsigned)f2bf(b.y) << 16);
  o.w = (unsigned)f2bf(b.z) | ((unsigned)f2bf(b.w) << 16);
  ((uint4*)out)[i] = o;
}

// ---------------- W [K][N] fp32 -> Wt [N][K] bf16 (64x64 tiles) ----------------
__global__ __launch_bounds__(256) void transpose_cast_kernel(const float* __restrict__ W,
                                                             unsigned short* __restrict__ Wt,
                                                             int K, int N) {
  __shared__ __align__(16) unsigned short tile[64 * 72];  // [n][k], pad 8
  int k0 = blockIdx.y * 64, n0 = blockIdx.x * 64;
  int t = threadIdx.x;
  int rr = t >> 4, cc = (t & 15) * 4;
#pragma unroll
  for (int p = 0; p < 4; ++p) {
    int k = rr + p * 16;
    float4 v = *(const float4*)&W[(size_t)(k0 + k) * N + n0 + cc];
    tile[(cc + 0) * 72 + k] = f2bf(v.x);
    tile[(cc + 1) * 72 + k] = f2bf(v.y);
    tile[(cc + 2) * 72 + k] = f2bf(v.z);
    tile[(cc + 3) * 72 + k] = f2bf(v.w);
  }
  __syncthreads();
  int n = t >> 2, c = (t & 3) * 16;
  float4* dst = (float4*)&Wt[(size_t)(n0 + n) * K + k0 + c];
  dst[0] = *(float4*)&tile[n * 72 + c];
  dst[1] = *(float4*)&tile[n * 72 + c + 8];
}

// ---------------- GEMM: C = A[M][K] * Bt[N][K]^T + bias ----------------
// m97 structure: global_load_lds width-16 into linear [128][32] tiles.
// mode 0: QKV epilogue -> q,k fp32 scatter into qkvf[2][NH][SALL][HD], v bf16 -> Vt[NH][HD][SALL]
// mode 2: plain fp32 C[M][N] -> outf
__global__ __launch_bounds__(256) void gemm_bt(const unsigned short* __restrict__ A,
                                               const unsigned short* __restrict__ Bt,
                                               const float* __restrict__ bias,
                                               int M, int N, int K, int mode,
                                               float* __restrict__ outf,
                                               unsigned short* __restrict__ outb, int s_off) {
  __shared__ __align__(16) unsigned short As[128 * 32];
  __shared__ __align__(16) unsigned short Bs[128 * 32];
  const int tid = threadIdx.x;
  const int wave = tid >> 6, lane = tid & 63, quad = lane >> 4, l16 = lane & 15;
  const int wm = (wave >> 1) * 64, wn = (wave & 1) * 64;
  const size_t m0 = (size_t)blockIdx.y * 128, n0 = (size_t)blockIdx.x * 128;

  ffrag zf = {0.f, 0.f, 0.f, 0.f};
  ffrag acc[4][4];
#pragma unroll
  for (int i = 0; i < 4; ++i)
#pragma unroll
    for (int j = 0; j < 4; ++j) acc[i][j] = zf;

  // staging map: thread t -> row t>>2 (0..63), 16B chunk t&3. Wave w covers
  // LDS bytes [w*1024, w*1024+1024) linearly == base + lane*16 (gload_lds req).
  const int sr = tid >> 2;
  const int sc = (tid & 3) * 8;
  const unsigned short* Ag0 = A + (m0 + sr) * K + sc;
  const unsigned short* Bg0 = Bt + (n0 + sr) * K + sc;
  unsigned short* Ad0 = &As[sr * 32 + sc];
  unsigned short* Ad1 = &As[(sr + 64) * 32 + sc];
  unsigned short* Bd0 = &Bs[sr * 32 + sc];
  unsigned short* Bd1 = &Bs[(sr + 64) * 32 + sc];

  for (int k0 = 0; k0 < K; k0 += 32) {
    __syncthreads();
    gload16(Ad0, Ag0 + k0);
    gload16(Ad1, Ag0 + (size_t)64 * K + k0);
    gload16(Bd0, Bg0 + k0);
    gload16(Bd1, Bg0 + (size_t)64 * K + k0);
    __syncthreads();  // drains vmcnt -> tiles ready
    bfrag af[4], bfv[4];
#pragma unroll
    for (int mt = 0; mt < 4; ++mt)
      af[mt] = *(const bfrag*)&As[(wm + mt * 16 + l16) * 32 + quad * 8];
#pragma unroll
    for (int nt = 0; nt < 4; ++nt)
      bfv[nt] = *(const bfrag*)&Bs[(wn + nt * 16 + l16) * 32 + quad * 8];
#pragma unroll
    for (int mt = 0; mt < 4; ++mt)
#pragma unroll
      for (int nt = 0; nt < 4; ++nt)
        acc[mt][nt] = __builtin_amdgcn_mfma_f32_16x16x32_bf16(af[mt], bfv[nt], acc[mt][nt], 0, 0, 0);
  }

  float bv[4];
#pragma unroll
  for (int nt = 0; nt < 4; ++nt) bv[nt] = bias[n0 + wn + nt * 16 + l16];

#pragma unroll
  for (int mt = 0; mt < 4; ++mt) {
#pragma unroll
    for (int nt = 0; nt < 4; ++nt) {
      int gn = (int)n0 + wn + nt * 16 + l16;
#pragma unroll
      for (int r = 0; r < 4; ++r) {
        float v = acc[mt][nt][r] + bv[nt];
        int gm = (int)m0 + wm + mt * 16 + quad * 4 + r;
        if (mode == 2) {
          outf[(size_t)gm * N + gn] = v;
        } else {
          int which = gn / DM;
          int rr2 = gn - which * DM;
          int head = rr2 >> 7, d = rr2 & 127;
          int s = s_off + gm;
          if (which < 2)
            outf[(((size_t)which * NH + head) * SALL + s) * HD + d] = v;
          else
            outb[((size_t)head * HD + d) * SALL + s] = f2bf(v);
        }
      }
    }
  }
}

// ---------------- fused RMSNorm + RoPE on q,k ----------------
// qkvf: [2][NH][SALL][HD] fp32 -> Qb/Kb bf16 [NH][SALL][HD]
__global__ __launch_bounds__(256) void norm_rope_kernel(
    const float* __restrict__ qkvf, const float* __restrict__ gq, const float* __restrict__ gk,
    const float* __restrict__ gaq, const float* __restrict__ gak,
    const float* __restrict__ img_cos, const float* __restrict__ img_sin,
    const float* __restrict__ txt_cos, const float* __restrict__ txt_sin,
    unsigned short* __restrict__ Qb, unsigned short* __restrict__ Kb) {
  int wave = threadIdx.x >> 6, lane = threadIdx.x & 63;
  int row = blockIdx.x * 4 + wave;  // < 2*NH*SALL
  int which = row / (NH * SALL);
  int rem = row - which * (NH * SALL);
  int s = rem % SALL;
  float2 v = *(const float2*)&qkvf[(size_t)row * HD + lane * 2];
  float ss = v.x * v.x + v.y * v.y;
#pragma unroll
  for (int m = 1; m < 64; m <<= 1) ss += __shfl_xor(ss, m);
  float rinv = rsqrtf(ss * (1.0f / 128.0f) + 1e-6f);
  bool is_txt = s < STXT;
  int pos = is_txt ? s : s - STXT;
  const float* g = (which == 0) ? (is_txt ? gaq : gq) : (is_txt ? gak : gk);
  const float* ct = is_txt ? txt_cos : img_cos;
  const float* st = is_txt ? txt_sin : img_sin;
  float c = ct[pos * 64 + lane], sn = st[pos * 64 + lane];
  float x0 = v.x * rinv * g[lane * 2];
  float x1 = v.y * rinv * g[lane * 2 + 1];
  float o0 = x0 * c - x1 * sn;
  float o1 = x0 * sn + x1 * c;
  unsigned short* out = (which == 0 ? Qb : Kb) + (size_t)rem * HD + lane * 2;
  *(unsigned int*)out = (unsigned)f2bf(o0) | ((unsigned)f2bf(o1) << 16);
}

// ---------------- flash attention ----------------
// Q,K: [NH][SALL][HD] bf16; Vt: [NH][HD][SALL] bf16; attn: [SALL][NH*HD] bf16
// grid (SALL/64, NH), 256 threads; each wave owns 16 q-rows; key tiles of 64.
// LDS tiles are UNPADDED with XOR swizzle (chunk16 ^= row&7), loaded via
// global_load_lds with pre-permuted per-lane global source (rule #21: the
// source permutation and the read permutation are the same involution).
__global__ __launch_bounds__(256) void flash_kernel(const unsigned short* __restrict__ Q,
                                                    const unsigned short* __restrict__ Kg,
                                                    const unsigned short* __restrict__ Vt,
                                                    unsigned short* __restrict__ attn) {
  __shared__ __align__(16) unsigned short Kl[64 * 128];    // 16 KB, swizzled
  __shared__ __align__(16) unsigned short Vl[128 * 64];    // 16 KB, swizzled
  __shared__ __align__(16) unsigned short Pl[4 * 16 * 64]; // 8 KB, per-wave, swizzled
  const int h = blockIdx.y;
  const int qb = blockIdx.x * 64;
  const int tid = threadIdx.x;
  const int wave = tid >> 6, lane = tid & 63, quad = lane >> 4, l16 = lane & 15;
  const int l7 = l16 & 7;

  // Q fragments (A operand), rows qb + wave*16 + l16
  const unsigned short* qrow = Q + ((size_t)h * SALL + qb + wave * 16 + l16) * HD;
  bfrag aq[4];
#pragma unroll
  for (int kk = 0; kk < 4; ++kk) aq[kk] = *(const bfrag*)&qrow[kk * 32 + quad * 8];

  const unsigned short* Kh = Kg + (size_t)h * SALL * HD;
  const unsigned short* Vh = Vt + (size_t)h * HD * SALL;

  ffrag zf = {0.f, 0.f, 0.f, 0.f};
  ffrag o[8];
#pragma unroll
  for (int i = 0; i < 8; ++i) o[i] = zf;
  float m_r[4] = {-__builtin_inff(), -__builtin_inff(), -__builtin_inff(), -__builtin_inff()};
  float l_r[4] = {0.f, 0.f, 0.f, 0.f};
  const float sc = 0.08838834764831845f * 1.4426950408889634f;  // 1/sqrt(128) * log2(e)

  for (int kb = 0; kb < SALL; kb += 64) {
    __syncthreads();  // all waves done reading Kl/Vl of previous tile
    // stage K tile [64 rows][128 elems]: wave covers rows wave*16..+15,
    // 4 rows per issue; lane L -> row +L/16, dest chunk L%16 (linear),
    // src chunk (L%16)^(row&7) -> read-side XOR finds it.
#pragma unroll
    for (int p = 0; p < 4; ++p) {
      int r = wave * 16 + p * 4 + quad;
      int cs = l16 ^ (r & 7);
      gload16(&Kl[r * 128 + l16 * 8], &Kh[(size_t)(kb + r) * HD + cs * 8]);
    }
    // stage V^T tile [128 rows(d)][64 elems(key)]: 8 rows per issue.
#pragma unroll
    for (int p = 0; p < 4; ++p) {
      int r = wave * 32 + p * 8 + (lane >> 3);
      int cs = (lane & 7) ^ (r & 7);
      gload16(&Vl[r * 64 + (lane & 7) * 8], &Vh[(size_t)r * SALL + kb + cs * 8]);
    }
    __syncthreads();  // drains vmcnt -> K,V tiles ready

    // QK^T: 4 n-tiles of 16 keys; K read with swizzle (row&7 == l16&7)
    ffrag s_[4];
#pragma unroll
    for (int nt = 0; nt < 4; ++nt) s_[nt] = zf;
#pragma unroll
    for (int kk = 0; kk < 4; ++kk) {
#pragma unroll
      for (int nt = 0; nt < 4; ++nt) {
        bfrag kf = *(const bfrag*)&Kl[(nt * 16 + l16) * 128 + ((kk * 4 + quad) ^ l7) * 8];
        s_[nt] = __builtin_amdgcn_mfma_f32_16x16x32_bf16(aq[kk], kf, s_[nt], 0, 0, 0);
      }
    }
    // scale into exp2 domain
#pragma unroll
    for (int nt = 0; nt < 4; ++nt)
#pragma unroll
      for (int r = 0; r < 4; ++r) s_[nt][r] *= sc;

    float alpha[4], rowsum[4];
#pragma unroll
    for (int r = 0; r < 4; ++r) {
      float mx = fmaxf(fmaxf(s_[0][r], s_[1][r]), fmaxf(s_[2][r], s_[3][r]));
#pragma unroll
      for (int msk = 1; msk < 16; msk <<= 1) mx = fmaxf(mx, __shfl_xor(mx, msk));
      float mnew = fmaxf(m_r[r], mx);
      alpha[r] = exp2f(m_r[r] - mnew);
      m_r[r] = mnew;
      float rs = 0.f;
#pragma unroll
      for (int nt = 0; nt < 4; ++nt) {
        float p = exp2f(s_[nt][r] - mnew);
        s_[nt][r] = p;
        rs += p;
      }
#pragma unroll
      for (int msk = 1; msk < 16; msk <<= 1) rs += __shfl_xor(rs, msk);
      rowsum[r] = rs;
      l_r[r] = l_r[r] * alpha[r] + rowsum[r];
    }
    // rescale O
#pragma unroll
    for (int dt = 0; dt < 8; ++dt)
#pragma unroll
      for (int r = 0; r < 4; ++r) o[dt][r] *= alpha[r];
    // write P (C layout -> per-wave LDS region) as bf16, swizzled:
    // elem_in_row col ^ ((row&7)<<3)
#pragma unroll
    for (int r = 0; r < 4; ++r) {
      int prow = quad * 4 + r;
#pragma unroll
      for (int nt = 0; nt < 4; ++nt)
        Pl[wave * 1024 + prow * 64 + ((nt * 16 + l16) ^ ((prow & 7) << 3))] = f2bf(s_[nt][r]);
    }
    // NO barrier here: Pl is per-wave private; within-wave ds ordering via lgkmcnt.

    // PV: P is A operand [q][key], V^T rows are B operand (both swizzle-read)
    bfrag pf0 = *(const bfrag*)&Pl[wave * 1024 + l16 * 64 + ((quad)     ^ l7) * 8];
    bfrag pf1 = *(const bfrag*)&Pl[wave * 1024 + l16 * 64 + ((quad + 4) ^ l7) * 8];
#pragma unroll
    for (int dt = 0; dt < 8; ++dt) {
      bfrag vf0 = *(const bfrag*)&Vl[(dt * 16 + l16) * 64 + ((quad)     ^ l7) * 8];
      bfrag vf1 = *(const bfrag*)&Vl[(dt * 16 + l16) * 64 + ((quad + 4) ^ l7) * 8];
      o[dt] = __builtin_amdgcn_mfma_f32_16x16x32_bf16(pf0, vf0, o[dt], 0, 0, 0);
      o[dt] = __builtin_amdgcn_mfma_f32_16x16x32_bf16(pf1, vf1, o[dt], 0, 0, 0);
    }
  }

  // epilogue: normalize and write attn[s][h*HD + d]
  float linv[4];
#pragma unroll
  for (int r = 0; r < 4; ++r) linv[r] = 1.0f / l_r[r];
#pragma unroll
  for (int dt = 0; dt < 8; ++dt) {
#pragma unroll
    for (int r = 0; r < 4; ++r) {
      int s = qb + wave * 16 + quad * 4 + r;
      attn[(size_t)s * DM + h * HD + dt * 16 + l16] = f2bf(o[dt][r] * linv[r]);
    }
  }
}

// ---------------- launch ----------------
extern "C" void kernel_launch(void* const* d_in, const int* in_sizes, int n_in,
                              void* d_out, int out_size, void* d_ws, size_t ws_size,
                              hipStream_t stream) {
  const float* image = (const float*)d_in[0];
  const float* text = (const float*)d_in[1];
  const float* img_cos = (const float*)d_in[2];
  const float* img_sin = (const float*)d_in[3];
  const float* txt_cos = (const float*)d_in[4];
  const float* txt_sin = (const float*)d_in[5];
  const float* Wqkv = (const float*)d_in[6];
  const float* bqkv = (const float*)d_in[7];
  const float* Wadd = (const float*)d_in[8];
  const float* badd = (const float*)d_in[9];
  const float* gq = (const float*)d_in[10];
  const float* gk = (const float*)d_in[11];
  const float* gaq = (const float*)d_in[12];
  const float* gak = (const float*)d_in[13];
  const float* Wout = (const float*)d_in[14];
  const float* bout = (const float*)d_in[15];
  const float* Waddout = (const float*)d_in[16];
  const float* baddout = (const float*)d_in[17];

  char* ws = (char*)d_ws;
  size_t off = 0;
  // img_bf/txt_bf are dead after the QKV GEMMs; attn (same total size) aliases them.
  unsigned short* img_bf = (unsigned short*)(ws + off); off += (size_t)SIMG * DM * 2;      // 12.6 MB
  unsigned short* txt_bf = (unsigned short*)(ws + off); off += (size_t)STXT * DM * 2;      // 1.6 MB
  unsigned short* attn = img_bf;  // alias: [SALL][DM] bf16 = 14.2 MB, written by flash only
  unsigned short* Wqkv_t = (unsigned short*)(ws + off); off += (size_t)DM3 * DM * 2;       // 56.6 MB
  unsigned short* Wadd_t = (unsigned short*)(ws + off); off += (size_t)DM3 * DM * 2;       // 56.6 MB
  unsigned short* Wout_t = (unsigned short*)(ws + off); off += (size_t)DM * DM * 2;        // 18.9 MB
  unsigned short* Waddout_t = (unsigned short*)(ws + off); off += (size_t)DM * DM * 2;     // 18.9 MB
  float* qkvf = (float*)(ws + off); off += (size_t)2 * NH * SALL * HD * 4;                 // 56.6 MB
  unsigned short* Qb = (unsigned short*)(ws + off); off += (size_t)NH * SALL * HD * 2;     // 14.2 MB
  unsigned short* Kb = (unsigned short*)(ws + off); off += (size_t)NH * SALL * HD * 2;     // 14.2 MB
  unsigned short* Vtb = (unsigned short*)(ws + off); off += (size_t)NH * HD * SALL * 2;    // 14.2 MB
  if (off > ws_size) return;  // workspace too small: bail (will fail validation loudly)

  cast_kernel<<<SIMG * DM / 2048, 256, 0, stream>>>(image, img_bf);
  cast_kernel<<<STXT * DM / 2048, 256, 0, stream>>>(text, txt_bf);
  transpose_cast_kernel<<<dim3(DM3 / 64, DM / 64), 256, 0, stream>>>(Wqkv, Wqkv_t, DM, DM3);
  transpose_cast_kernel<<<dim3(DM3 / 64, DM / 64), 256, 0, stream>>>(Wadd, Wadd_t, DM, DM3);
  transpose_cast_kernel<<<dim3(DM / 64, DM / 64), 256, 0, stream>>>(Wout, Wout_t, DM, DM);
  transpose_cast_kernel<<<dim3(DM / 64, DM / 64), 256, 0, stream>>>(Waddout, Waddout_t, DM, DM);

  // QKV projections (epilogue scatters q,k fp32 + v bf16 transposed)
  gemm_bt<<<dim3(DM3 / 128, SIMG / 128), 256, 0, stream>>>(img_bf, Wqkv_t, bqkv, SIMG, DM3, DM,
                                                           0, qkvf, Vtb, STXT);
  gemm_bt<<<dim3(DM3 / 128, STXT / 128), 256, 0, stream>>>(txt_bf, Wadd_t, badd, STXT, DM3, DM,
                                                           0, qkvf, Vtb, 0);

  norm_rope_kernel<<<2 * NH * SALL / 4, 256, 0, stream>>>(qkvf, gq, gk, gaq, gak, img_cos,
                                                          img_sin, txt_cos, txt_sin, Qb, Kb);

  flash_kernel<<<dim3(SALL / 64, NH), 256, 0, stream>>>(Qb, Kb, Vtb, attn);

  // output projections straight into d_out (img_out first, then txt_out)
  gemm_bt<<<dim3(DM / 128, SIMG / 128), 256, 0, stream>>>(attn + (size_t)STXT * DM, Wout_t, bout,
                                                          SIMG, DM, DM, 2, (float*)d_out, nullptr, 0);
  gemm_bt<<<dim3(DM / 128, STXT / 128), 256, 0, stream>>>(attn, Waddout_t, baddout, STXT, DM, DM,
                                                          2, (float*)d_out + (size_t)SIMG * DM,
                                                          nullptr, 0);
}

// Round 2
// 1030.694 us; speedup vs baseline: 1.1084x; 1.1084x over previous
//
#include <hip/hip_runtime.h>

#define NH 24
#define HD 128
#define DM 3072
#define DM3 9216
#define STXT 256
#define SIMG 2048
#define SALL 2304

typedef __attribute__((ext_vector_type(8))) short bfrag;
typedef __attribute__((ext_vector_type(4))) float ffrag;

__device__ __forceinline__ unsigned short f2bf(float f) {
  unsigned int x = __builtin_bit_cast(unsigned int, f);
  x += 0x7fffu + ((x >> 16) & 1u);
  return (unsigned short)(x >> 16);
}

// async 16B global->LDS (DMA). LDS dest = wave-uniform base + lane*16.
__device__ __forceinline__ void gload16(void* lds, const void* g) {
  __builtin_amdgcn_global_load_lds((const __attribute__((address_space(1))) unsigned int*)g,
                                   (__attribute__((address_space(3))) unsigned int*)lds, 16, 0, 0);
}

// ---------------- cast fp32 -> bf16 (8 elems/thread) ----------------
__global__ __launch_bounds__(256) void cast_kernel(const float* __restrict__ in,
                                                   unsigned short* __restrict__ out) {
  int i = blockIdx.x * 256 + threadIdx.x;
  float4 a = ((const float4*)in)[2 * i];
  float4 b = ((const float4*)in)[2 * i + 1];
  uint4 o;
  o.x = (unsigned)f2bf(a.x) | ((unsigned)f2bf(a.y) << 16);
  o.y = (unsigned)f2bf(a.z) | ((unsigned)f2bf(a.w) << 16);
  o.z = (unsigned)f2bf(b.x) | ((unsigned)f2bf(b.y) << 16);
  o.w = (unsigned)f2bf(b.z) | ((unsigned)f2bf(b.w) << 16);
  ((uint4*)out)[i] = o;
}

// ---------------- W [K][N] fp32 -> Wt [N][K] bf16 (64x64 tiles) ----------------
__global__ __launch_bounds__(256) void transpose_cast_kernel(const float* __restrict__ W,
                                                             unsigned short* __restrict__ Wt,
                                                             int K, int N) {
  __shared__ __align__(16) unsigned short tile[64 * 72];  // [n][k], pad 8
  int k0 = blockIdx.y * 64, n0 = blockIdx.x * 64;
  int t = threadIdx.x;
  int rr = t >> 4, cc = (t & 15) * 4;
#pragma unroll
  for (int p = 0; p < 4; ++p) {
    int k = rr + p * 16;
    float4 v = *(const float4*)&W[(size_t)(k0 + k) * N + n0 + cc];
    tile[(cc + 0) * 72 + k] = f2bf(v.x);
    tile[(cc + 1) * 72 + k] = f2bf(v.y);
    tile[(cc + 2) * 72 + k] = f2bf(v.z);
    tile[(cc + 3) * 72 + k] = f2bf(v.w);
  }
  __syncthreads();
  int n = t >> 2, c = (t & 3) * 16;
  float4* dst = (float4*)&Wt[(size_t)(n0 + n) * K + k0 + c];
  dst[0] = *(float4*)&tile[n * 72 + c];
  dst[1] = *(float4*)&tile[n * 72 + c + 8];
}

// ---------------- GEMM: C = A[M][K] * Bt[N][K]^T + bias ----------------
// m97 structure: global_load_lds width-16 into linear [128][32] tiles.
// mode 0: QKV epilogue -> q,k fp32 scatter into qkvf[2][NH][SALL][HD], v bf16 -> Vt[NH][HD][SALL]
// mode 2: plain fp32 C[M][N] -> outf
__global__ __launch_bounds__(256) void gemm_bt(const unsigned short* __restrict__ A,
                                               const unsigned short* __restrict__ Bt,
                                               const float* __restrict__ bias,
                                               int M, int N, int K, int mode,
                                               float* __restrict__ outf,
                                               unsigned short* __restrict__ outb, int s_off) {
  __shared__ __align__(16) unsigned short As[128 * 32];
  __shared__ __align__(16) unsigned short Bs[128 * 32];
  const int tid = threadIdx.x;
  const int wave = tid >> 6, lane = tid & 63, quad = lane >> 4, l16 = lane & 15;
  const int wm = (wave >> 1) * 64, wn = (wave & 1) * 64;
  const size_t m0 = (size_t)blockIdx.y * 128, n0 = (size_t)blockIdx.x * 128;

  ffrag zf = {0.f, 0.f, 0.f, 0.f};
  ffrag acc[4][4];
#pragma unroll
  for (int i = 0; i < 4; ++i)
#pragma unroll
    for (int j = 0; j < 4; ++j) acc[i][j] = zf;

  const int sr = tid >> 2;
  const int sc = (tid & 3) * 8;
  const unsigned short* Ag0 = A + (m0 + sr) * K + sc;
  const unsigned short* Bg0 = Bt + (n0 + sr) * K + sc;
  unsigned short* Ad0 = &As[sr * 32 + sc];
  unsigned short* Ad1 = &As[(sr + 64) * 32 + sc];
  unsigned short* Bd0 = &Bs[sr * 32 + sc];
  unsigned short* Bd1 = &Bs[(sr + 64) * 32 + sc];

  for (int k0 = 0; k0 < K; k0 += 32) {
    __syncthreads();
    gload16(Ad0, Ag0 + k0);
    gload16(Ad1, Ag0 + (size_t)64 * K + k0);
    gload16(Bd0, Bg0 + k0);
    gload16(Bd1, Bg0 + (size_t)64 * K + k0);
    __syncthreads();  // drains vmcnt -> tiles ready
    bfrag af[4], bfv[4];
#pragma unroll
    for (int mt = 0; mt < 4; ++mt)
      af[mt] = *(const bfrag*)&As[(wm + mt * 16 + l16) * 32 + quad * 8];
#pragma unroll
    for (int nt = 0; nt < 4; ++nt)
      bfv[nt] = *(const bfrag*)&Bs[(wn + nt * 16 + l16) * 32 + quad * 8];
#pragma unroll
    for (int mt = 0; mt < 4; ++mt)
#pragma unroll
      for (int nt = 0; nt < 4; ++nt)
        acc[mt][nt] = __builtin_amdgcn_mfma_f32_16x16x32_bf16(af[mt], bfv[nt], acc[mt][nt], 0, 0, 0);
  }

  float bv[4];
#pragma unroll
  for (int nt = 0; nt < 4; ++nt) bv[nt] = bias[n0 + wn + nt * 16 + l16];

#pragma unroll
  for (int mt = 0; mt < 4; ++mt) {
#pragma unroll
    for (int nt = 0; nt < 4; ++nt) {
      int gn = (int)n0 + wn + nt * 16 + l16;
#pragma unroll
      for (int r = 0; r < 4; ++r) {
        float v = acc[mt][nt][r] + bv[nt];
        int gm = (int)m0 + wm + mt * 16 + quad * 4 + r;
        if (mode == 2) {
          outf[(size_t)gm * N + gn] = v;
        } else {
          int which = gn / DM;
          int rr2 = gn - which * DM;
          int head = rr2 >> 7, d = rr2 & 127;
          int s = s_off + gm;
          if (which < 2)
            outf[(((size_t)which * NH + head) * SALL + s) * HD + d] = v;
          else
            outb[((size_t)head * HD + d) * SALL + s] = f2bf(v);
        }
      }
    }
  }
}

// ---------------- fused RMSNorm + RoPE on q,k ----------------
__global__ __launch_bounds__(256) void norm_rope_kernel(
    const float* __restrict__ qkvf, const float* __restrict__ gq, const float* __restrict__ gk,
    const float* __restrict__ gaq, const float* __restrict__ gak,
    const float* __restrict__ img_cos, const float* __restrict__ img_sin,
    const float* __restrict__ txt_cos, const float* __restrict__ txt_sin,
    unsigned short* __restrict__ Qb, unsigned short* __restrict__ Kb) {
  int wave = threadIdx.x >> 6, lane = threadIdx.x & 63;
  int row = blockIdx.x * 4 + wave;  // < 2*NH*SALL
  int which = row / (NH * SALL);
  int rem = row - which * (NH * SALL);
  int s = rem % SALL;
  float2 v = *(const float2*)&qkvf[(size_t)row * HD + lane * 2];
  float ss = v.x * v.x + v.y * v.y;
#pragma unroll
  for (int m = 1; m < 64; m <<= 1) ss += __shfl_xor(ss, m);
  float rinv = rsqrtf(ss * (1.0f / 128.0f) + 1e-6f);
  bool is_txt = s < STXT;
  int pos = is_txt ? s : s - STXT;
  const float* g = (which == 0) ? (is_txt ? gaq : gq) : (is_txt ? gak : gk);
  const float* ct = is_txt ? txt_cos : img_cos;
  const float* st = is_txt ? txt_sin : img_sin;
  float c = ct[pos * 64 + lane], sn = st[pos * 64 + lane];
  float x0 = v.x * rinv * g[lane * 2];
  float x1 = v.y * rinv * g[lane * 2 + 1];
  float o0 = x0 * c - x1 * sn;
  float o1 = x0 * sn + x1 * c;
  unsigned short* out = (which == 0 ? Qb : Kb) + (size_t)rem * HD + lane * 2;
  *(unsigned int*)out = (unsigned)f2bf(o0) | ((unsigned)f2bf(o1) << 16);
}

// ---------------- flash attention ----------------
// Q,K: [NH][SALL][HD] bf16; Vt: [NH][HD][SALL] bf16; attn: [SALL][NH*HD] bf16
// 1D grid of 864 blocks, XCD-pinned: each XCD (bid%8) owns 108 contiguous
// work items = exactly 3 heads -> per-XCD L2 working set (K+V) ~3.5 MB < 4 MB.
// Staging: reg->ds_write with XOR swizzle (chunk16 ^= row&7), T14 split:
// next tile's global loads issued before compute so HBM latency hides under it.
__global__ __launch_bounds__(256) void flash_kernel(const unsigned short* __restrict__ Q,
                                                    const unsigned short* __restrict__ Kg,
                                                    const unsigned short* __restrict__ Vt,
                                                    unsigned short* __restrict__ attn) {
  __shared__ __align__(16) unsigned short Kl[64 * 128];    // 16 KB, swizzled
  __shared__ __align__(16) unsigned short Vl[128 * 64];    // 16 KB, swizzled
  __shared__ __align__(16) unsigned short Pl[4 * 16 * 64]; // 8 KB, per-wave, swizzled
  // bijective chunked XCD swizzle: 864 = 8 * 108, 108 = 3 heads * 36 q-blocks
  int bid = blockIdx.x;
  int g = (bid & 7) * 108 + (bid >> 3);
  const int h = g / 36;
  const int qb = (g - h * 36) * 64;
  const int tid = threadIdx.x;
  const int wave = tid >> 6, lane = tid & 63, quad = lane >> 4, l16 = lane & 15;
  const int l7 = l16 & 7;

  // Q fragments (A operand), rows qb + wave*16 + l16
  const unsigned short* qrow = Q + ((size_t)h * SALL + qb + wave * 16 + l16) * HD;
  bfrag aq[4];
#pragma unroll
  for (int kk = 0; kk < 4; ++kk) aq[kk] = *(const bfrag*)&qrow[kk * 32 + quad * 8];

  const unsigned short* Kh = Kg + (size_t)h * SALL * HD;
  const unsigned short* Vh = Vt + (size_t)h * HD * SALL;

  // staging maps (all 256 threads cooperate):
  // K [64 rows][16 chunks]: row kr+p*16, chunk kc ; V [128 rows][8 chunks]: row vr+p*32, chunk vc
  const int kr = tid >> 4, kc = tid & 15;
  const int vr = tid >> 3, vc = tid & 7;
  const int kswz = kc ^ (kr & 7);  // p*16 doesn't change row&7
  const int vswz = vc ^ (vr & 7);  // p*32 doesn't change row&7

  ffrag zf = {0.f, 0.f, 0.f, 0.f};
  ffrag o[8];
#pragma unroll
  for (int i = 0; i < 8; ++i) o[i] = zf;
  float m_r[4] = {-__builtin_inff(), -__builtin_inff(), -__builtin_inff(), -__builtin_inff()};
  float l_r[4] = {0.f, 0.f, 0.f, 0.f};
  const float sc = 0.08838834764831845f * 1.4426950408889634f;  // 1/sqrt(128) * log2(e)

  // prologue: load tile 0 into registers
  bfrag kreg[4], vreg[4];
#pragma unroll
  for (int p = 0; p < 4; ++p) {
    kreg[p] = *(const bfrag*)&Kh[(size_t)(kr + p * 16) * HD + kc * 8];
    vreg[p] = *(const bfrag*)&Vh[(size_t)(vr + p * 32) * SALL + vc * 8];
  }

  for (int t = 0; t < SALL / 64; ++t) {
    __syncthreads();  // all waves done reading prev tile (also drains prefetch vmcnt)
    // ds_write staged regs, swizzled
#pragma unroll
    for (int p = 0; p < 4; ++p) {
      *(bfrag*)&Kl[(kr + p * 16) * 128 + kswz * 8] = kreg[p];
      *(bfrag*)&Vl[(vr + p * 32) * 64 + vswz * 8] = vreg[p];
    }
    __syncthreads();  // lgkm drained -> tiles visible, regs free

    // T14: issue next tile's loads now; latency hides under compute below
    if (t + 1 < SALL / 64) {
      int kn = (t + 1) * 64;
#pragma unroll
      for (int p = 0; p < 4; ++p) {
        kreg[p] = *(const bfrag*)&Kh[(size_t)(kn + kr + p * 16) * HD + kc * 8];
        vreg[p] = *(const bfrag*)&Vh[(size_t)(vr + p * 32) * SALL + kn + vc * 8];
      }
    }

    // QK^T: 4 n-tiles of 16 keys; K read swizzled (row&7 == l16&7)
    ffrag s_[4];
#pragma unroll
    for (int nt = 0; nt < 4; ++nt) s_[nt] = zf;
#pragma unroll
    for (int kk = 0; kk < 4; ++kk) {
#pragma unroll
      for (int nt = 0; nt < 4; ++nt) {
        bfrag kf = *(const bfrag*)&Kl[(nt * 16 + l16) * 128 + ((kk * 4 + quad) ^ l7) * 8];
        s_[nt] = __builtin_amdgcn_mfma_f32_16x16x32_bf16(aq[kk], kf, s_[nt], 0, 0, 0);
      }
    }
    // scale into exp2 domain
#pragma unroll
    for (int nt = 0; nt < 4; ++nt)
#pragma unroll
      for (int r = 0; r < 4; ++r) s_[nt][r] *= sc;

    float alpha[4];
#pragma unroll
    for (int r = 0; r < 4; ++r) {
      float mx = fmaxf(fmaxf(s_[0][r], s_[1][r]), fmaxf(s_[2][r], s_[3][r]));
#pragma unroll
      for (int msk = 1; msk < 16; msk <<= 1) mx = fmaxf(mx, __shfl_xor(mx, msk));
      float mnew = fmaxf(m_r[r], mx);
      alpha[r] = exp2f(m_r[r] - mnew);
      m_r[r] = mnew;
      float rs = 0.f;
#pragma unroll
      for (int nt = 0; nt < 4; ++nt) {
        float p = exp2f(s_[nt][r] - mnew);
        s_[nt][r] = p;
        rs += p;
      }
#pragma unroll
      for (int msk = 1; msk < 16; msk <<= 1) rs += __shfl_xor(rs, msk);
      l_r[r] = l_r[r] * alpha[r] + rs;
    }
    // rescale O
#pragma unroll
    for (int dt = 0; dt < 8; ++dt)
#pragma unroll
      for (int r = 0; r < 4; ++r) o[dt][r] *= alpha[r];
    // write P (C layout -> per-wave LDS region) as bf16, swizzled
#pragma unroll
    for (int r = 0; r < 4; ++r) {
      int prow = quad * 4 + r;
#pragma unroll
      for (int nt = 0; nt < 4; ++nt)
        Pl[wave * 1024 + prow * 64 + ((nt * 16 + l16) ^ ((prow & 7) << 3))] = f2bf(s_[nt][r]);
    }
    // no barrier: Pl region is per-wave private; within-wave ds ordering via lgkmcnt

    // PV: P is A operand [q][key], V^T rows are B operand (both swizzle-read)
    bfrag pf0 = *(const bfrag*)&Pl[wave * 1024 + l16 * 64 + ((quad)     ^ l7) * 8];
    bfrag pf1 = *(const bfrag*)&Pl[wave * 1024 + l16 * 64 + ((quad + 4) ^ l7) * 8];
#pragma unroll
    for (int dt = 0; dt < 8; ++dt) {
      bfrag vf0 = *(const bfrag*)&Vl[(dt * 16 + l16) * 64 + ((quad)     ^ l7) * 8];
      bfrag vf1 = *(const bfrag*)&Vl[(dt * 16 + l16) * 64 + ((quad + 4) ^ l7) * 8];
      o[dt] = __builtin_amdgcn_mfma_f32_16x16x32_bf16(pf0, vf0, o[dt], 0, 0, 0);
      o[dt] = __builtin_amdgcn_mfma_f32_16x16x32_bf16(pf1, vf1, o[dt], 0, 0, 0);
    }
  }

  // epilogue: normalize and write attn[s][h*HD + d]
  float linv[4];
#pragma unroll
  for (int r = 0; r < 4; ++r) linv[r] = 1.0f / l_r[r];
#pragma unroll
  for (int dt = 0; dt < 8; ++dt) {
#pragma unroll
    for (int r = 0; r < 4; ++r) {
      int s = qb + wave * 16 + quad * 4 + r;
      attn[(size_t)s * DM + h * HD + dt * 16 + l16] = f2bf(o[dt][r] * linv[r]);
    }
  }
}

// ---------------- launch ----------------
extern "C" void kernel_launch(void* const* d_in, const int* in_sizes, int n_in,
                              void* d_out, int out_size, void* d_ws, size_t ws_size,
                              hipStream_t stream) {
  const float* image = (const float*)d_in[0];
  const float* text = (const float*)d_in[1];
  const float* img_cos = (const float*)d_in[2];
  const float* img_sin = (const float*)d_in[3];
  const float* txt_cos = (const float*)d_in[4];
  const float* txt_sin = (const float*)d_in[5];
  const float* Wqkv = (const float*)d_in[6];
  const float* bqkv = (const float*)d_in[7];
  const float* Wadd = (const float*)d_in[8];
  const float* badd = (const float*)d_in[9];
  const float* gq = (const float*)d_in[10];
  const float* gk = (const float*)d_in[11];
  const float* gaq = (const float*)d_in[12];
  const float* gak = (const float*)d_in[13];
  const float* Wout = (const float*)d_in[14];
  const float* bout = (const float*)d_in[15];
  const float* Waddout = (const float*)d_in[16];
  const float* baddout = (const float*)d_in[17];

  char* ws = (char*)d_ws;
  size_t off = 0;
  // img_bf/txt_bf are dead after the QKV GEMMs; attn (same total size) aliases them.
  unsigned short* img_bf = (unsigned short*)(ws + off); off += (size_t)SIMG * DM * 2;      // 12.6 MB
  unsigned short* txt_bf = (unsigned short*)(ws + off); off += (size_t)STXT * DM * 2;      // 1.6 MB
  unsigned short* attn = img_bf;  // alias: [SALL][DM] bf16 = 14.2 MB, written by flash only
  unsigned short* Wqkv_t = (unsigned short*)(ws + off); off += (size_t)DM3 * DM * 2;       // 56.6 MB
  unsigned short* Wadd_t = (unsigned short*)(ws + off); off += (size_t)DM3 * DM * 2;       // 56.6 MB
  unsigned short* Wout_t = (unsigned short*)(ws + off); off += (size_t)DM * DM * 2;        // 18.9 MB
  unsigned short* Waddout_t = (unsigned short*)(ws + off); off += (size_t)DM * DM * 2;     // 18.9 MB
  float* qkvf = (float*)(ws + off); off += (size_t)2 * NH * SALL * HD * 4;                 // 56.6 MB
  unsigned short* Qb = (unsigned short*)(ws + off); off += (size_t)NH * SALL * HD * 2;     // 14.2 MB
  unsigned short* Kb = (unsigned short*)(ws + off); off += (size_t)NH * SALL * HD * 2;     // 14.2 MB
  unsigned short* Vtb = (unsigned short*)(ws + off); off += (size_t)NH * HD * SALL * 2;    // 14.2 MB
  if (off > ws_size) return;  // workspace too small: bail (will fail validation loudly)

  cast_kernel<<<SIMG * DM / 2048, 256, 0, stream>>>(image, img_bf);
  cast_kernel<<<STXT * DM / 2048, 256, 0, stream>>>(text, txt_bf);
  transpose_cast_kernel<<<dim3(DM3 / 64, DM / 64), 256, 0, stream>>>(Wqkv, Wqkv_t, DM, DM3);
  transpose_cast_kernel<<<dim3(DM3 / 64, DM / 64), 256, 0, stream>>>(Wadd, Wadd_t, DM, DM3);
  transpose_cast_kernel<<<dim3(DM / 64, DM / 64), 256, 0, stream>>>(Wout, Wout_t, DM, DM);
  transpose_cast_kernel<<<dim3(DM / 64, DM / 64), 256, 0, stream>>>(Waddout, Waddout_t, DM, DM);

  // QKV projections (epilogue scatters q,k fp32 + v bf16 transposed)
  gemm_bt<<<dim3(DM3 / 128, SIMG / 128), 256, 0, stream>>>(img_bf, Wqkv_t, bqkv, SIMG, DM3, DM,
                                                           0, qkvf, Vtb, STXT);
  gemm_bt<<<dim3(DM3 / 128, STXT / 128), 256, 0, stream>>>(txt_bf, Wadd_t, badd, STXT, DM3, DM,
                                                           0, qkvf, Vtb, 0);

  norm_rope_kernel<<<2 * NH * SALL / 4, 256, 0, stream>>>(qkvf, gq, gk, gaq, gak, img_cos,
                                                          img_sin, txt_cos, txt_sin, Qb, Kb);

  flash_kernel<<<dim3(SALL / 64 * NH), 256, 0, stream>>>(Qb, Kb, Vtb, attn);

  // output projections straight into d_out (img_out first, then txt_out)
  gemm_bt<<<dim3(DM / 128, SIMG / 128), 256, 0, stream>>>(attn + (size_t)STXT * DM, Wout_t, bout,
                                                          SIMG, DM, DM, 2, (float*)d_out, nullptr, 0);
  gemm_bt<<<dim3(DM / 128, STXT / 128), 256, 0, stream>>>(attn, Waddout_t, baddout, STXT, DM, DM,
                                                          2, (float*)d_out + (size_t)SIMG * DM,
                                                          nullptr, 0);
}

// Round 3
// 999.683 us; speedup vs baseline: 1.1428x; 1.0310x over previous
//
#include <hip/hip_runtime.h>

#define NH 24
#define HD 128
#define DM 3072
#define DM3 9216
#define STXT 256
#define SIMG 2048
#define SALL 2304

typedef __attribute__((ext_vector_type(8))) short bfrag;
typedef __attribute__((ext_vector_type(4))) float ffrag;

__device__ __forceinline__ unsigned short f2bf(float f) {
  unsigned int x = __builtin_bit_cast(unsigned int, f);
  x += 0x7fffu + ((x >> 16) & 1u);
  return (unsigned short)(x >> 16);
}

// async 16B global->LDS (DMA). LDS dest = wave-uniform base + lane*16.
__device__ __forceinline__ void gload16(void* lds, const void* g) {
  __builtin_amdgcn_global_load_lds((const __attribute__((address_space(1))) unsigned int*)g,
                                   (__attribute__((address_space(3))) unsigned int*)lds, 16, 0, 0);
}

// ---------------- cast fp32 -> bf16 (8 elems/thread) ----------------
__global__ __launch_bounds__(256) void cast_kernel(const float* __restrict__ in,
                                                   unsigned short* __restrict__ out) {
  int i = blockIdx.x * 256 + threadIdx.x;
  float4 a = ((const float4*)in)[2 * i];
  float4 b = ((const float4*)in)[2 * i + 1];
  uint4 o;
  o.x = (unsigned)f2bf(a.x) | ((unsigned)f2bf(a.y) << 16);
  o.y = (unsigned)f2bf(a.z) | ((unsigned)f2bf(a.w) << 16);
  o.z = (unsigned)f2bf(b.x) | ((unsigned)f2bf(b.y) << 16);
  o.w = (unsigned)f2bf(b.z) | ((unsigned)f2bf(b.w) << 16);
  ((uint4*)out)[i] = o;
}

// ---------------- W [K][N] fp32 -> Wt [N][K] bf16 (64x64 tiles) ----------------
__global__ __launch_bounds__(256) void transpose_cast_kernel(const float* __restrict__ W,
                                                             unsigned short* __restrict__ Wt,
                                                             int K, int N) {
  __shared__ __align__(16) unsigned short tile[64 * 72];  // [n][k], pad 8
  int k0 = blockIdx.y * 64, n0 = blockIdx.x * 64;
  int t = threadIdx.x;
  int rr = t >> 4, cc = (t & 15) * 4;
#pragma unroll
  for (int p = 0; p < 4; ++p) {
    int k = rr + p * 16;
    float4 v = *(const float4*)&W[(size_t)(k0 + k) * N + n0 + cc];
    tile[(cc + 0) * 72 + k] = f2bf(v.x);
    tile[(cc + 1) * 72 + k] = f2bf(v.y);
    tile[(cc + 2) * 72 + k] = f2bf(v.z);
    tile[(cc + 3) * 72 + k] = f2bf(v.w);
  }
  __syncthreads();
  int n = t >> 2, c = (t & 3) * 16;
  float4* dst = (float4*)&Wt[(size_t)(n0 + n) * K + k0 + c];
  dst[0] = *(float4*)&tile[n * 72 + c];
  dst[1] = *(float4*)&tile[n * 72 + c + 8];
}

// ---------------- 256x256 8-phase GEMM: C = A[M][K] * Bt[N][K]^T + bias ----------------
// 512 threads = 8 waves (2 row x 4 col), per-wave C = 128x64, BK=64.
// LDS 128 KiB: 2 bufs x (A 256x64 + B 256x64), each as 2 halves of 128x64 bf16.
// T2 swizzle: linear gload_lds dest + pre-swizzled global src chunk; ds_read XORs back.
// T3/T4: counted vmcnt(8) (tile t's loads issued 2 K-tiles before their wait);
// stage of tile t+2 into buf[cur] issued only after the barrier ending all buf[cur] reads.
// Row-region select: block m0==0 -> txt (B_txt/bias_txt), else img.
// mode 0: QKV scatter epilogue; mode 2: fp32 rows to out_txt/out_img.
#define STAGE256(tt, c)                                                                          \
  {                                                                                              \
    const size_t kof = (size_t)(tt)*64;                                                          \
    _Pragma("unroll") for (int hf = 0; hf < 2; ++hf) {                                           \
      _Pragma("unroll") for (int i = 0; i < 2; ++i) {                                            \
        gload16(&SA[c][hf][i * 4096 + sdst], Asrc + (size_t)(hf * 128 + i * 64) * K + kof);      \
        gload16(&SB[c][hf][i * 4096 + sdst], Bsrc + (size_t)(hf * 128 + i * 64) * K + kof);      \
      }                                                                                          \
    }                                                                                            \
  }

#define RDA(QM)                                                                       \
  _Pragma("unroll") for (int mi = 0; mi < 4; ++mi) {                                  \
    a_[mi * 2 + 0] = *(const bfrag*)&Ab[((QM)*64 + mi * 16 + l16) * 64 + ck0];        \
    a_[mi * 2 + 1] = *(const bfrag*)&Ab[((QM)*64 + mi * 16 + l16) * 64 + ck1];        \
  }

#define RDB(QN, DST)                                                                  \
  _Pragma("unroll") for (int ni = 0; ni < 2; ++ni) {                                  \
    DST[ni * 2 + 0] = *(const bfrag*)&Bb[((QN)*32 + ni * 16 + l16) * 64 + ck0];       \
    DST[ni * 2 + 1] = *(const bfrag*)&Bb[((QN)*32 + ni * 16 + l16) * 64 + ck1];       \
  }

#define MQUAD(QM, QN, BOP)                                                            \
  _Pragma("unroll") for (int mi = 0; mi < 4; ++mi) {                                  \
    _Pragma("unroll") for (int ni = 0; ni < 2; ++ni) {                                \
      _Pragma("unroll") for (int kk = 0; kk < 2; ++kk) {                              \
        acc[(QM)*4 + mi][(QN)*2 + ni] = __builtin_amdgcn_mfma_f32_16x16x32_bf16(      \
            a_[mi * 2 + kk], BOP[ni * 2 + kk], acc[(QM)*4 + mi][(QN)*2 + ni], 0, 0, 0); \
      }                                                                               \
    }                                                                                 \
  }

__global__ __launch_bounds__(512, 2) void gemm256(const unsigned short* __restrict__ A,
                                                  const unsigned short* __restrict__ Bt_txt,
                                                  const unsigned short* __restrict__ Bt_img,
                                                  const float* __restrict__ bias_txt,
                                                  const float* __restrict__ bias_img,
                                                  int N, int K, int mode,
                                                  float* __restrict__ qkvf,
                                                  unsigned short* __restrict__ vtb,
                                                  float* __restrict__ out_txt,
                                                  float* __restrict__ out_img) {
  __shared__ __align__(16) unsigned short SA[2][2][8192];
  __shared__ __align__(16) unsigned short SB[2][2][8192];
  const int tid = threadIdx.x;
  const int wave = tid >> 6, lane = tid & 63, quad = lane >> 4, l16 = lane & 15;
  const int wr = wave >> 2, wc = wave & 3;
  const int m0 = blockIdx.y * 256, n0 = blockIdx.x * 256;
  const unsigned short* Bt = (m0 == 0) ? Bt_txt : Bt_img;
  const float* bias = (m0 == 0) ? bias_txt : bias_img;

  // staging map: thread -> row wave*8 + lane/8 (of 64-row issue region), 16B chunk lane%8.
  // source chunk pre-swizzled so linear LDS + XOR'd read = st-swizzle (rule #21).
  const int srow = wave * 8 + (lane >> 3);
  const int scs = ((lane & 7) ^ (((lane >> 5) & 1) << 1)) * 8;
  const int sdst = wave * 512 + lane * 8;
  const unsigned short* Asrc = A + (size_t)(m0 + srow) * K + scs;
  const unsigned short* Bsrc = Bt + (size_t)(n0 + srow) * K + scs;

  // read-side swizzled chunk offsets (row bit2 == l16 bit2 for all frag rows)
  const int aswz = ((l16 >> 2) & 1) << 1;
  const int ck0 = ((quad)&3 ^ aswz) * 8;
  const int ck1 = ((quad + 4) ^ aswz) * 8;

  ffrag zf = {0.f, 0.f, 0.f, 0.f};
  ffrag acc[8][4];
#pragma unroll
  for (int i = 0; i < 8; ++i)
#pragma unroll
    for (int j = 0; j < 4; ++j) acc[i][j] = zf;

  const int NT = K >> 6;
  // prologue: stage tiles 0,1 (16 loads in flight)
  STAGE256(0, 0);
  STAGE256(1, 1);

  for (int t = 0; t < NT; ++t) {
    const int cur = t & 1;
    if (t + 1 < NT) {
      asm volatile("s_waitcnt vmcnt(8)" ::: "memory");  // tile t landed; t+1 may fly
    } else {
      asm volatile("s_waitcnt vmcnt(0)" ::: "memory");  // last tile: drain
    }
    __builtin_amdgcn_sched_barrier(0);
    __builtin_amdgcn_s_barrier();  // B0: staged buf[cur] visible to all waves
    __builtin_amdgcn_sched_barrier(0);

    const unsigned short* Ab = &SA[cur][wr][0];
    const unsigned short* Bb = &SB[cur][wc >> 1][(wc & 1) * 4096];
    bfrag a_[8], b0_[4], b1_[4];

    // ---- P0: quad(0,0) ----
    RDA(0);
    RDB(0, b0_);
    __builtin_amdgcn_s_barrier();
    asm volatile("s_waitcnt lgkmcnt(0)" ::: "memory");
    __builtin_amdgcn_sched_barrier(0);
    __builtin_amdgcn_s_setprio(1);
    MQUAD(0, 0, b0_);
    __builtin_amdgcn_s_setprio(0);
    __builtin_amdgcn_s_barrier();

    // ---- P1: quad(0,1) ----
    RDB(1, b1_);
    __builtin_amdgcn_s_barrier();
    asm volatile("s_waitcnt lgkmcnt(0)" ::: "memory");
    __builtin_amdgcn_sched_barrier(0);
    __builtin_amdgcn_s_setprio(1);
    MQUAD(0, 1, b1_);
    __builtin_amdgcn_s_setprio(0);
    __builtin_amdgcn_s_barrier();

    // ---- P2: quad(1,0) ----
    RDA(1);
    __builtin_amdgcn_s_barrier();
    asm volatile("s_waitcnt lgkmcnt(0)" ::: "memory");
    __builtin_amdgcn_sched_barrier(0);
    __builtin_amdgcn_s_setprio(1);
    MQUAD(1, 0, b0_);
    __builtin_amdgcn_s_setprio(0);
    __builtin_amdgcn_s_barrier();  // after this, all reads of buf[cur] are done
    __builtin_amdgcn_sched_barrier(0);

    // ---- P3: stage tile t+2 into freed buf[cur], then quad(1,1) ----
    if (t + 2 < NT) STAGE256(t + 2, cur);
    __builtin_amdgcn_sched_barrier(0);
    __builtin_amdgcn_s_setprio(1);
    MQUAD(1, 1, b1_);
    __builtin_amdgcn_s_setprio(0);
    // next-iter top: vmcnt + B0 double as P3's closing barrier
  }

  // epilogue
#pragma unroll
  for (int a = 0; a < 8; ++a) {
    const int rowb = m0 + wr * 128 + (a >> 2) * 64 + (a & 3) * 16 + quad * 4;
#pragma unroll
    for (int b = 0; b < 4; ++b) {
      const int gn = n0 + wc * 64 + (b >> 1) * 32 + (b & 1) * 16 + l16;
      const float bv = bias[gn];
#pragma unroll
      for (int r = 0; r < 4; ++r) {
        float v = acc[a][b][r] + bv;
        int gm = rowb + r;
        if (mode == 2) {
          if (gm < STXT)
            out_txt[(size_t)gm * N + gn] = v;
          else
            out_img[(size_t)(gm - STXT) * N + gn] = v;
        } else {
          int which = gn / DM;
          int rr2 = gn - which * DM;
          int head = rr2 >> 7, d = rr2 & 127;
          if (which < 2)
            qkvf[(((size_t)which * NH + head) * SALL + gm) * HD + d] = v;
          else
            vtb[((size_t)head * HD + d) * SALL + gm] = f2bf(v);
        }
      }
    }
  }
}

// ---------------- fused RMSNorm + RoPE on q,k ----------------
__global__ __launch_bounds__(256) void norm_rope_kernel(
    const float* __restrict__ qkvf, const float* __restrict__ gq, const float* __restrict__ gk,
    const float* __restrict__ gaq, const float* __restrict__ gak,
    const float* __restrict__ img_cos, const float* __restrict__ img_sin,
    const float* __restrict__ txt_cos, const float* __restrict__ txt_sin,
    unsigned short* __restrict__ Qb, unsigned short* __restrict__ Kb) {
  int wave = threadIdx.x >> 6, lane = threadIdx.x & 63;
  int row = blockIdx.x * 4 + wave;  // < 2*NH*SALL
  int which = row / (NH * SALL);
  int rem = row - which * (NH * SALL);
  int s = rem % SALL;
  float2 v = *(const float2*)&qkvf[(size_t)row * HD + lane * 2];
  float ss = v.x * v.x + v.y * v.y;
#pragma unroll
  for (int m = 1; m < 64; m <<= 1) ss += __shfl_xor(ss, m);
  float rinv = rsqrtf(ss * (1.0f / 128.0f) + 1e-6f);
  bool is_txt = s < STXT;
  int pos = is_txt ? s : s - STXT;
  const float* g = (which == 0) ? (is_txt ? gaq : gq) : (is_txt ? gak : gk);
  const float* ct = is_txt ? txt_cos : img_cos;
  const float* st = is_txt ? txt_sin : img_sin;
  float c = ct[pos * 64 + lane], sn = st[pos * 64 + lane];
  float x0 = v.x * rinv * g[lane * 2];
  float x1 = v.y * rinv * g[lane * 2 + 1];
  float o0 = x0 * c - x1 * sn;
  float o1 = x0 * sn + x1 * c;
  unsigned short* out = (which == 0 ? Qb : Kb) + (size_t)rem * HD + lane * 2;
  *(unsigned int*)out = (unsigned)f2bf(o0) | ((unsigned)f2bf(o1) << 16);
}

// ---------------- flash attention (unchanged from R2) ----------------
__global__ __launch_bounds__(256) void flash_kernel(const unsigned short* __restrict__ Q,
                                                    const unsigned short* __restrict__ Kg,
                                                    const unsigned short* __restrict__ Vt,
                                                    unsigned short* __restrict__ attn) {
  __shared__ __align__(16) unsigned short Kl[64 * 128];    // 16 KB, swizzled
  __shared__ __align__(16) unsigned short Vl[128 * 64];    // 16 KB, swizzled
  __shared__ __align__(16) unsigned short Pl[4 * 16 * 64]; // 8 KB, per-wave, swizzled
  // bijective chunked XCD swizzle: 864 = 8 * 108, 108 = 3 heads * 36 q-blocks
  int bid = blockIdx.x;
  int g = (bid & 7) * 108 + (bid >> 3);
  const int h = g / 36;
  const int qb = (g - h * 36) * 64;
  const int tid = threadIdx.x;
  const int wave = tid >> 6, lane = tid & 63, quad = lane >> 4, l16 = lane & 15;
  const int l7 = l16 & 7;

  const unsigned short* qrow = Q + ((size_t)h * SALL + qb + wave * 16 + l16) * HD;
  bfrag aq[4];
#pragma unroll
  for (int kk = 0; kk < 4; ++kk) aq[kk] = *(const bfrag*)&qrow[kk * 32 + quad * 8];

  const unsigned short* Kh = Kg + (size_t)h * SALL * HD;
  const unsigned short* Vh = Vt + (size_t)h * HD * SALL;

  const int kr = tid >> 4, kc = tid & 15;
  const int vr = tid >> 3, vc = tid & 7;
  const int kswz = kc ^ (kr & 7);
  const int vswz = vc ^ (vr & 7);

  ffrag zf = {0.f, 0.f, 0.f, 0.f};
  ffrag o[8];
#pragma unroll
  for (int i = 0; i < 8; ++i) o[i] = zf;
  float m_r[4] = {-__builtin_inff(), -__builtin_inff(), -__builtin_inff(), -__builtin_inff()};
  float l_r[4] = {0.f, 0.f, 0.f, 0.f};
  const float sc = 0.08838834764831845f * 1.4426950408889634f;  // 1/sqrt(128) * log2(e)

  bfrag kreg[4], vreg[4];
#pragma unroll
  for (int p = 0; p < 4; ++p) {
    kreg[p] = *(const bfrag*)&Kh[(size_t)(kr + p * 16) * HD + kc * 8];
    vreg[p] = *(const bfrag*)&Vh[(size_t)(vr + p * 32) * SALL + vc * 8];
  }

  for (int t = 0; t < SALL / 64; ++t) {
    __syncthreads();
#pragma unroll
    for (int p = 0; p < 4; ++p) {
      *(bfrag*)&Kl[(kr + p * 16) * 128 + kswz * 8] = kreg[p];
      *(bfrag*)&Vl[(vr + p * 32) * 64 + vswz * 8] = vreg[p];
    }
    __syncthreads();

    if (t + 1 < SALL / 64) {
      int kn = (t + 1) * 64;
#pragma unroll
      for (int p = 0; p < 4; ++p) {
        kreg[p] = *(const bfrag*)&Kh[(size_t)(kn + kr + p * 16) * HD + kc * 8];
        vreg[p] = *(const bfrag*)&Vh[(size_t)(vr + p * 32) * SALL + kn + vc * 8];
      }
    }

    ffrag s_[4];
#pragma unroll
    for (int nt = 0; nt < 4; ++nt) s_[nt] = zf;
#pragma unroll
    for (int kk = 0; kk < 4; ++kk) {
#pragma unroll
      for (int nt = 0; nt < 4; ++nt) {
        bfrag kf = *(const bfrag*)&Kl[(nt * 16 + l16) * 128 + ((kk * 4 + quad) ^ l7) * 8];
        s_[nt] = __builtin_amdgcn_mfma_f32_16x16x32_bf16(aq[kk], kf, s_[nt], 0, 0, 0);
      }
    }
#pragma unroll
    for (int nt = 0; nt < 4; ++nt)
#pragma unroll
      for (int r = 0; r < 4; ++r) s_[nt][r] *= sc;

    float alpha[4];
#pragma unroll
    for (int r = 0; r < 4; ++r) {
      float mx = fmaxf(fmaxf(s_[0][r], s_[1][r]), fmaxf(s_[2][r], s_[3][r]));
#pragma unroll
      for (int msk = 1; msk < 16; msk <<= 1) mx = fmaxf(mx, __shfl_xor(mx, msk));
      float mnew = fmaxf(m_r[r], mx);
      alpha[r] = exp2f(m_r[r] - mnew);
      m_r[r] = mnew;
      float rs = 0.f;
#pragma unroll
      for (int nt = 0; nt < 4; ++nt) {
        float p = exp2f(s_[nt][r] - mnew);
        s_[nt][r] = p;
        rs += p;
      }
#pragma unroll
      for (int msk = 1; msk < 16; msk <<= 1) rs += __shfl_xor(rs, msk);
      l_r[r] = l_r[r] * alpha[r] + rs;
    }
#pragma unroll
    for (int dt = 0; dt < 8; ++dt)
#pragma unroll
      for (int r = 0; r < 4; ++r) o[dt][r] *= alpha[r];
#pragma unroll
    for (int r = 0; r < 4; ++r) {
      int prow = quad * 4 + r;
#pragma unroll
      for (int nt = 0; nt < 4; ++nt)
        Pl[wave * 1024 + prow * 64 + ((nt * 16 + l16) ^ ((prow & 7) << 3))] = f2bf(s_[nt][r]);
    }

    bfrag pf0 = *(const bfrag*)&Pl[wave * 1024 + l16 * 64 + ((quad)     ^ l7) * 8];
    bfrag pf1 = *(const bfrag*)&Pl[wave * 1024 + l16 * 64 + ((quad + 4) ^ l7) * 8];
#pragma unroll
    for (int dt = 0; dt < 8; ++dt) {
      bfrag vf0 = *(const bfrag*)&Vl[(dt * 16 + l16) * 64 + ((quad)     ^ l7) * 8];
      bfrag vf1 = *(const bfrag*)&Vl[(dt * 16 + l16) * 64 + ((quad + 4) ^ l7) * 8];
      o[dt] = __builtin_amdgcn_mfma_f32_16x16x32_bf16(pf0, vf0, o[dt], 0, 0, 0);
      o[dt] = __builtin_amdgcn_mfma_f32_16x16x32_bf16(pf1, vf1, o[dt], 0, 0, 0);
    }
  }

  float linv[4];
#pragma unroll
  for (int r = 0; r < 4; ++r) linv[r] = 1.0f / l_r[r];
#pragma unroll
  for (int dt = 0; dt < 8; ++dt) {
#pragma unroll
    for (int r = 0; r < 4; ++r) {
      int s = qb + wave * 16 + quad * 4 + r;
      attn[(size_t)s * DM + h * HD + dt * 16 + l16] = f2bf(o[dt][r] * linv[r]);
    }
  }
}

// ---------------- launch ----------------
extern "C" void kernel_launch(void* const* d_in, const int* in_sizes, int n_in,
                              void* d_out, int out_size, void* d_ws, size_t ws_size,
                              hipStream_t stream) {
  const float* image = (const float*)d_in[0];
  const float* text = (const float*)d_in[1];
  const float* img_cos = (const float*)d_in[2];
  const float* img_sin = (const float*)d_in[3];
  const float* txt_cos = (const float*)d_in[4];
  const float* txt_sin = (const float*)d_in[5];
  const float* Wqkv = (const float*)d_in[6];
  const float* bqkv = (const float*)d_in[7];
  const float* Wadd = (const float*)d_in[8];
  const float* badd = (const float*)d_in[9];
  const float* gq = (const float*)d_in[10];
  const float* gk = (const float*)d_in[11];
  const float* gaq = (const float*)d_in[12];
  const float* gak = (const float*)d_in[13];
  const float* Wout = (const float*)d_in[14];
  const float* bout = (const float*)d_in[15];
  const float* Waddout = (const float*)d_in[16];
  const float* baddout = (const float*)d_in[17];

  char* ws = (char*)d_ws;
  size_t off = 0;
  // x_bf: [SALL][DM] bf16, txt rows 0-255 then img rows (matches attention s-order).
  // Dead after QKV GEMM; attn (same size) aliases it.
  unsigned short* x_bf = (unsigned short*)(ws + off); off += (size_t)SALL * DM * 2;        // 14.2 MB
  unsigned short* attn = x_bf;  // alias: [SALL][DM] bf16, written by flash only
  unsigned short* Wqkv_t = (unsigned short*)(ws + off); off += (size_t)DM3 * DM * 2;       // 56.6 MB
  unsigned short* Wadd_t = (unsigned short*)(ws + off); off += (size_t)DM3 * DM * 2;       // 56.6 MB
  unsigned short* Wout_t = (unsigned short*)(ws + off); off += (size_t)DM * DM * 2;        // 18.9 MB
  unsigned short* Waddout_t = (unsigned short*)(ws + off); off += (size_t)DM * DM * 2;     // 18.9 MB
  float* qkvf = (float*)(ws + off); off += (size_t)2 * NH * SALL * HD * 4;                 // 56.6 MB
  unsigned short* Qb = (unsigned short*)(ws + off); off += (size_t)NH * SALL * HD * 2;     // 14.2 MB
  unsigned short* Kb = (unsigned short*)(ws + off); off += (size_t)NH * SALL * HD * 2;     // 14.2 MB
  unsigned short* Vtb = (unsigned short*)(ws + off); off += (size_t)NH * HD * SALL * 2;    // 14.2 MB
  if (off > ws_size) return;

  cast_kernel<<<STXT * DM / 2048, 256, 0, stream>>>(text, x_bf);
  cast_kernel<<<SIMG * DM / 2048, 256, 0, stream>>>(image, x_bf + (size_t)STXT * DM);
  transpose_cast_kernel<<<dim3(DM3 / 64, DM / 64), 256, 0, stream>>>(Wqkv, Wqkv_t, DM, DM3);
  transpose_cast_kernel<<<dim3(DM3 / 64, DM / 64), 256, 0, stream>>>(Wadd, Wadd_t, DM, DM3);
  transpose_cast_kernel<<<dim3(DM / 64, DM / 64), 256, 0, stream>>>(Wout, Wout_t, DM, DM);
  transpose_cast_kernel<<<dim3(DM / 64, DM / 64), 256, 0, stream>>>(Waddout, Waddout_t, DM, DM);

  // merged QKV projection: block-row 0 = txt (Wadd/badd), rest = img (Wqkv/bqkv)
  gemm256<<<dim3(DM3 / 256, SALL / 256), 512, 0, stream>>>(
      x_bf, Wadd_t, Wqkv_t, badd, bqkv, DM3, DM, 0, qkvf, Vtb, nullptr, nullptr);

  norm_rope_kernel<<<2 * NH * SALL / 4, 256, 0, stream>>>(qkvf, gq, gk, gaq, gak, img_cos,
                                                          img_sin, txt_cos, txt_sin, Qb, Kb);

  flash_kernel<<<dim3(SALL / 64 * NH), 256, 0, stream>>>(Qb, Kb, Vtb, attn);

  // merged output projection: block-row 0 = txt (Waddout->d_out tail), rest = img (Wout->d_out head)
  gemm256<<<dim3(DM / 256, SALL / 256), 512, 0, stream>>>(
      attn, Waddout_t, Wout_t, baddout, bout, DM, DM, 2, nullptr, nullptr,
      (float*)d_out + (size_t)SIMG * DM, (float*)d_out);
}

// Round 4
// 991.628 us; speedup vs baseline: 1.1521x; 1.0081x over previous
//
#include <hip/hip_runtime.h>

#define NH 24
#define HD 128
#define DM 3072
#define DM3 9216
#define STXT 256
#define SIMG 2048
#define SALL 2304

typedef __attribute__((ext_vector_type(8))) short bfrag;
typedef __attribute__((ext_vector_type(4))) float ffrag;

__device__ __forceinline__ unsigned short f2bf(float f) {
  unsigned int x = __builtin_bit_cast(unsigned int, f);
  x += 0x7fffu + ((x >> 16) & 1u);
  return (unsigned short)(x >> 16);
}

// async 16B global->LDS (DMA). LDS dest = wave-uniform base + lane*16.
__device__ __forceinline__ void gload16(void* lds, const void* g) {
  __builtin_amdgcn_global_load_lds((const __attribute__((address_space(1))) unsigned int*)g,
                                   (__attribute__((address_space(3))) unsigned int*)lds, 16, 0, 0);
}

// ---------------- cast fp32 -> bf16 (8 elems/thread) ----------------
__global__ __launch_bounds__(256) void cast_kernel(const float* __restrict__ in,
                                                   unsigned short* __restrict__ out) {
  int i = blockIdx.x * 256 + threadIdx.x;
  float4 a = ((const float4*)in)[2 * i];
  float4 b = ((const float4*)in)[2 * i + 1];
  uint4 o;
  o.x = (unsigned)f2bf(a.x) | ((unsigned)f2bf(a.y) << 16);
  o.y = (unsigned)f2bf(a.z) | ((unsigned)f2bf(a.w) << 16);
  o.z = (unsigned)f2bf(b.x) | ((unsigned)f2bf(b.y) << 16);
  o.w = (unsigned)f2bf(b.z) | ((unsigned)f2bf(b.w) << 16);
  ((uint4*)out)[i] = o;
}

// ---------------- W [K][N] fp32 -> Wt [N][K] bf16 (64x64 tiles) ----------------
__global__ __launch_bounds__(256) void transpose_cast_kernel(const float* __restrict__ W,
                                                             unsigned short* __restrict__ Wt,
                                                             int K, int N) {
  __shared__ __align__(16) unsigned short tile[64 * 72];  // [n][k], pad 8
  int k0 = blockIdx.y * 64, n0 = blockIdx.x * 64;
  int t = threadIdx.x;
  int rr = t >> 4, cc = (t & 15) * 4;
#pragma unroll
  for (int p = 0; p < 4; ++p) {
    int k = rr + p * 16;
    float4 v = *(const float4*)&W[(size_t)(k0 + k) * N + n0 + cc];
    tile[(cc + 0) * 72 + k] = f2bf(v.x);
    tile[(cc + 1) * 72 + k] = f2bf(v.y);
    tile[(cc + 2) * 72 + k] = f2bf(v.z);
    tile[(cc + 3) * 72 + k] = f2bf(v.w);
  }
  __syncthreads();
  int n = t >> 2, c = (t & 3) * 16;
  float4* dst = (float4*)&Wt[(size_t)(n0 + n) * K + k0 + c];
  dst[0] = *(float4*)&tile[n * 72 + c];
  dst[1] = *(float4*)&tile[n * 72 + c + 8];
}

// ---------------- 256x256 8-phase GEMM: C = A[M][K] * Bt[N][K]^T + bias ----------------
// 512 threads = 8 waves (2 row x 4 col), per-wave C = 128x64, BK=64.
// LDS 128 KiB: 2 bufs x (A 256x64 + B 256x64), each as 2 halves of 128x64 bf16.
// T2 swizzle (FULL 3-bit): LDS(row, c) holds global (row, c ^ (row&7)).
//   write side: linear gload_lds dest + pre-swizzled global src chunk (lane&7)^((lane>>3)&7)
//   read side:  chunk ^ (l16&7)  (all frag rows are ==l16 mod 8)
//   -> every ds_read_b128 spreads 64 lanes over all 8 16B-slots (8 lanes/slot = free).
// T3/T4: counted vmcnt(8); stage of tile t+2 only after the barrier ending buf[cur] reads.
// Grid: 1D, XCD-chunked bijective (m204), row-major tiles so each XCD chunk shares A panels.
#define STAGE256(tt, c)                                                                          \
  {                                                                                              \
    const size_t kof = (size_t)(tt)*64;                                                          \
    _Pragma("unroll") for (int hf = 0; hf < 2; ++hf) {                                           \
      _Pragma("unroll") for (int i = 0; i < 2; ++i) {                                            \
        gload16(&SA[c][hf][i * 4096 + sdst], Asrc + (size_t)(hf * 128 + i * 64) * K + kof);      \
        gload16(&SB[c][hf][i * 4096 + sdst], Bsrc + (size_t)(hf * 128 + i * 64) * K + kof);      \
      }                                                                                          \
    }                                                                                            \
  }

#define RDA(QM)                                                                       \
  _Pragma("unroll") for (int mi = 0; mi < 4; ++mi) {                                  \
    a_[mi * 2 + 0] = *(const bfrag*)&Ab[((QM)*64 + mi * 16 + l16) * 64 + ck0];        \
    a_[mi * 2 + 1] = *(const bfrag*)&Ab[((QM)*64 + mi * 16 + l16) * 64 + ck1];        \
  }

#define RDB(QN, DST)                                                                  \
  _Pragma("unroll") for (int ni = 0; ni < 2; ++ni) {                                  \
    DST[ni * 2 + 0] = *(const bfrag*)&Bb[((QN)*32 + ni * 16 + l16) * 64 + ck0];       \
    DST[ni * 2 + 1] = *(const bfrag*)&Bb[((QN)*32 + ni * 16 + l16) * 64 + ck1];       \
  }

#define MQUAD(QM, QN, BOP)                                                            \
  _Pragma("unroll") for (int mi = 0; mi < 4; ++mi) {                                  \
    _Pragma("unroll") for (int ni = 0; ni < 2; ++ni) {                                \
      _Pragma("unroll") for (int kk = 0; kk < 2; ++kk) {                              \
        acc[(QM)*4 + mi][(QN)*2 + ni] = __builtin_amdgcn_mfma_f32_16x16x32_bf16(      \
            a_[mi * 2 + kk], BOP[ni * 2 + kk], acc[(QM)*4 + mi][(QN)*2 + ni], 0, 0, 0); \
      }                                                                               \
    }                                                                                 \
  }

__global__ __launch_bounds__(512, 2) void gemm256(const unsigned short* __restrict__ A,
                                                  const unsigned short* __restrict__ Bt_txt,
                                                  const unsigned short* __restrict__ Bt_img,
                                                  const float* __restrict__ bias_txt,
                                                  const float* __restrict__ bias_img,
                                                  int N, int K, int ncols, int mode,
                                                  float* __restrict__ qkvf,
                                                  unsigned short* __restrict__ vtb,
                                                  float* __restrict__ out_txt,
                                                  float* __restrict__ out_img) {
  __shared__ __align__(16) unsigned short SA[2][2][8192];
  __shared__ __align__(16) unsigned short SB[2][2][8192];
  const int tid = threadIdx.x;
  const int wave = tid >> 6, lane = tid & 63, quad = lane >> 4, l16 = lane & 15;
  const int wr = wave >> 2, wc = wave & 3;
  // XCD-chunked bijective block swizzle (m204), row-major tile order
  const int nwg = gridDim.x;
  const int q8 = nwg >> 3, r8 = nwg & 7;
  const int xcd = blockIdx.x & 7, idx = blockIdx.x >> 3;
  const int wg = (xcd < r8 ? xcd * (q8 + 1) : r8 * (q8 + 1) + (xcd - r8) * q8) + idx;
  const int m0 = (wg / ncols) * 256, n0 = (wg % ncols) * 256;
  const unsigned short* Bt = (m0 == 0) ? Bt_txt : Bt_img;
  const float* bias = (m0 == 0) ? bias_txt : bias_img;

  // staging map: thread -> row wave*8 + lane/8 (of each 64-row issue region), chunk lane%8.
  // full 3-bit pre-swizzle on the SOURCE chunk; LDS dest stays linear (gload_lds req).
  const int srow = wave * 8 + (lane >> 3);
  const int scs = ((lane & 7) ^ (srow & 7)) * 8;
  const int sdst = wave * 512 + lane * 8;
  const unsigned short* Asrc = A + (size_t)(m0 + srow) * K + scs;
  const unsigned short* Bsrc = Bt + (size_t)(n0 + srow) * K + scs;

  // read-side swizzle: all frag rows == l16 (mod 8)
  const int rsw = l16 & 7;
  const int ck0 = (quad ^ rsw) * 8;
  const int ck1 = ((quad + 4) ^ rsw) * 8;

  ffrag zf = {0.f, 0.f, 0.f, 0.f};
  ffrag acc[8][4];
#pragma unroll
  for (int i = 0; i < 8; ++i)
#pragma unroll
    for (int j = 0; j < 4; ++j) acc[i][j] = zf;

  const int NT = K >> 6;
  // prologue: stage tiles 0,1 (16 loads in flight)
  STAGE256(0, 0);
  STAGE256(1, 1);

  for (int t = 0; t < NT; ++t) {
    const int cur = t & 1;
    if (t + 1 < NT) {
      asm volatile("s_waitcnt vmcnt(8)" ::: "memory");  // tile t landed; t+1 may fly
    } else {
      asm volatile("s_waitcnt vmcnt(0)" ::: "memory");  // last tile: drain
    }
    __builtin_amdgcn_sched_barrier(0);
    __builtin_amdgcn_s_barrier();  // B0: staged buf[cur] visible to all waves
    __builtin_amdgcn_sched_barrier(0);

    const unsigned short* Ab = &SA[cur][wr][0];
    const unsigned short* Bb = &SB[cur][wc >> 1][(wc & 1) * 4096];
    bfrag a_[8], b0_[4], b1_[4];

    // ---- P0: quad(0,0) ----
    RDA(0);
    RDB(0, b0_);
    __builtin_amdgcn_s_barrier();
    asm volatile("s_waitcnt lgkmcnt(0)" ::: "memory");
    __builtin_amdgcn_sched_barrier(0);
    __builtin_amdgcn_s_setprio(1);
    MQUAD(0, 0, b0_);
    __builtin_amdgcn_s_setprio(0);
    __builtin_amdgcn_s_barrier();

    // ---- P1: quad(0,1) ----
    RDB(1, b1_);
    __builtin_amdgcn_s_barrier();
    asm volatile("s_waitcnt lgkmcnt(0)" ::: "memory");
    __builtin_amdgcn_sched_barrier(0);
    __builtin_amdgcn_s_setprio(1);
    MQUAD(0, 1, b1_);
    __builtin_amdgcn_s_setprio(0);
    __builtin_amdgcn_s_barrier();

    // ---- P2: quad(1,0) ----
    RDA(1);
    __builtin_amdgcn_s_barrier();
    asm volatile("s_waitcnt lgkmcnt(0)" ::: "memory");
    __builtin_amdgcn_sched_barrier(0);
    __builtin_amdgcn_s_setprio(1);
    MQUAD(1, 0, b0_);
    __builtin_amdgcn_s_setprio(0);
    __builtin_amdgcn_s_barrier();  // after this, all reads of buf[cur] are done
    __builtin_amdgcn_sched_barrier(0);

    // ---- P3: stage tile t+2 into freed buf[cur], then quad(1,1) ----
    if (t + 2 < NT) STAGE256(t + 2, cur);
    __builtin_amdgcn_sched_barrier(0);
    __builtin_amdgcn_s_setprio(1);
    MQUAD(1, 1, b1_);
    __builtin_amdgcn_s_setprio(0);
    // next-iter top: vmcnt + B0 double as P3's closing barrier
  }

  // epilogue
#pragma unroll
  for (int a = 0; a < 8; ++a) {
    const int rowb = m0 + wr * 128 + (a >> 2) * 64 + (a & 3) * 16 + quad * 4;
#pragma unroll
    for (int b = 0; b < 4; ++b) {
      const int gn = n0 + wc * 64 + (b >> 1) * 32 + (b & 1) * 16 + l16;
      const float bv = bias[gn];
#pragma unroll
      for (int r = 0; r < 4; ++r) {
        float v = acc[a][b][r] + bv;
        int gm = rowb + r;
        if (mode == 2) {
          if (gm < STXT)
            out_txt[(size_t)gm * N + gn] = v;
          else
            out_img[(size_t)(gm - STXT) * N + gn] = v;
        } else {
          int which = gn / DM;
          int rr2 = gn - which * DM;
          int head = rr2 >> 7, d = rr2 & 127;
          if (which < 2)
            qkvf[(((size_t)which * NH + head) * SALL + gm) * HD + d] = v;
          else
            vtb[((size_t)head * HD + d) * SALL + gm] = f2bf(v);
        }
      }
    }
  }
}

// ---------------- fused RMSNorm + RoPE on q,k ----------------
__global__ __launch_bounds__(256) void norm_rope_kernel(
    const float* __restrict__ qkvf, const float* __restrict__ gq, const float* __restrict__ gk,
    const float* __restrict__ gaq, const float* __restrict__ gak,
    const float* __restrict__ img_cos, const float* __restrict__ img_sin,
    const float* __restrict__ txt_cos, const float* __restrict__ txt_sin,
    unsigned short* __restrict__ Qb, unsigned short* __restrict__ Kb) {
  int wave = threadIdx.x >> 6, lane = threadIdx.x & 63;
  int row = blockIdx.x * 4 + wave;  // < 2*NH*SALL
  int which = row / (NH * SALL);
  int rem = row - which * (NH * SALL);
  int s = rem % SALL;
  float2 v = *(const float2*)&qkvf[(size_t)row * HD + lane * 2];
  float ss = v.x * v.x + v.y * v.y;
#pragma unroll
  for (int m = 1; m < 64; m <<= 1) ss += __shfl_xor(ss, m);
  float rinv = rsqrtf(ss * (1.0f / 128.0f) + 1e-6f);
  bool is_txt = s < STXT;
  int pos = is_txt ? s : s - STXT;
  const float* g = (which == 0) ? (is_txt ? gaq : gq) : (is_txt ? gak : gk);
  const float* ct = is_txt ? txt_cos : img_cos;
  const float* st = is_txt ? txt_sin : img_sin;
  float c = ct[pos * 64 + lane], sn = st[pos * 64 + lane];
  float x0 = v.x * rinv * g[lane * 2];
  float x1 = v.y * rinv * g[lane * 2 + 1];
  float o0 = x0 * c - x1 * sn;
  float o1 = x0 * sn + x1 * c;
  unsigned short* out = (which == 0 ? Qb : Kb) + (size_t)rem * HD + lane * 2;
  *(unsigned int*)out = (unsigned)f2bf(o0) | ((unsigned)f2bf(o1) << 16);
}

// ---------------- flash attention (unchanged from R2) ----------------
__global__ __launch_bounds__(256) void flash_kernel(const unsigned short* __restrict__ Q,
                                                    const unsigned short* __restrict__ Kg,
                                                    const unsigned short* __restrict__ Vt,
                                                    unsigned short* __restrict__ attn) {
  __shared__ __align__(16) unsigned short Kl[64 * 128];    // 16 KB, swizzled
  __shared__ __align__(16) unsigned short Vl[128 * 64];    // 16 KB, swizzled
  __shared__ __align__(16) unsigned short Pl[4 * 16 * 64]; // 8 KB, per-wave, swizzled
  // bijective chunked XCD swizzle: 864 = 8 * 108, 108 = 3 heads * 36 q-blocks
  int bid = blockIdx.x;
  int g = (bid & 7) * 108 + (bid >> 3);
  const int h = g / 36;
  const int qb = (g - h * 36) * 64;
  const int tid = threadIdx.x;
  const int wave = tid >> 6, lane = tid & 63, quad = lane >> 4, l16 = lane & 15;
  const int l7 = l16 & 7;

  const unsigned short* qrow = Q + ((size_t)h * SALL + qb + wave * 16 + l16) * HD;
  bfrag aq[4];
#pragma unroll
  for (int kk = 0; kk < 4; ++kk) aq[kk] = *(const bfrag*)&qrow[kk * 32 + quad * 8];

  const unsigned short* Kh = Kg + (size_t)h * SALL * HD;
  const unsigned short* Vh = Vt + (size_t)h * HD * SALL;

  const int kr = tid >> 4, kc = tid & 15;
  const int vr = tid >> 3, vc = tid & 7;
  const int kswz = kc ^ (kr & 7);
  const int vswz = vc ^ (vr & 7);

  ffrag zf = {0.f, 0.f, 0.f, 0.f};
  ffrag o[8];
#pragma unroll
  for (int i = 0; i < 8; ++i) o[i] = zf;
  float m_r[4] = {-__builtin_inff(), -__builtin_inff(), -__builtin_inff(), -__builtin_inff()};
  float l_r[4] = {0.f, 0.f, 0.f, 0.f};
  const float sc = 0.08838834764831845f * 1.4426950408889634f;  // 1/sqrt(128) * log2(e)

  bfrag kreg[4], vreg[4];
#pragma unroll
  for (int p = 0; p < 4; ++p) {
    kreg[p] = *(const bfrag*)&Kh[(size_t)(kr + p * 16) * HD + kc * 8];
    vreg[p] = *(const bfrag*)&Vh[(size_t)(vr + p * 32) * SALL + vc * 8];
  }

  for (int t = 0; t < SALL / 64; ++t) {
    __syncthreads();
#pragma unroll
    for (int p = 0; p < 4; ++p) {
      *(bfrag*)&Kl[(kr + p * 16) * 128 + kswz * 8] = kreg[p];
      *(bfrag*)&Vl[(vr + p * 32) * 64 + vswz * 8] = vreg[p];
    }
    __syncthreads();

    if (t + 1 < SALL / 64) {
      int kn = (t + 1) * 64;
#pragma unroll
      for (int p = 0; p < 4; ++p) {
        kreg[p] = *(const bfrag*)&Kh[(size_t)(kn + kr + p * 16) * HD + kc * 8];
        vreg[p] = *(const bfrag*)&Vh[(size_t)(vr + p * 32) * SALL + kn + vc * 8];
      }
    }

    ffrag s_[4];
#pragma unroll
    for (int nt = 0; nt < 4; ++nt) s_[nt] = zf;
#pragma unroll
    for (int kk = 0; kk < 4; ++kk) {
#pragma unroll
      for (int nt = 0; nt < 4; ++nt) {
        bfrag kf = *(const bfrag*)&Kl[(nt * 16 + l16) * 128 + ((kk * 4 + quad) ^ l7) * 8];
        s_[nt] = __builtin_amdgcn_mfma_f32_16x16x32_bf16(aq[kk], kf, s_[nt], 0, 0, 0);
      }
    }
#pragma unroll
    for (int nt = 0; nt < 4; ++nt)
#pragma unroll
      for (int r = 0; r < 4; ++r) s_[nt][r] *= sc;

    float alpha[4];
#pragma unroll
    for (int r = 0; r < 4; ++r) {
      float mx = fmaxf(fmaxf(s_[0][r], s_[1][r]), fmaxf(s_[2][r], s_[3][r]));
#pragma unroll
      for (int msk = 1; msk < 16; msk <<= 1) mx = fmaxf(mx, __shfl_xor(mx, msk));
      float mnew = fmaxf(m_r[r], mx);
      alpha[r] = exp2f(m_r[r] - mnew);
      m_r[r] = mnew;
      float rs = 0.f;
#pragma unroll
      for (int nt = 0; nt < 4; ++nt) {
        float p = exp2f(s_[nt][r] - mnew);
        s_[nt][r] = p;
        rs += p;
      }
#pragma unroll
      for (int msk = 1; msk < 16; msk <<= 1) rs += __shfl_xor(rs, msk);
      l_r[r] = l_r[r] * alpha[r] + rs;
    }
#pragma unroll
    for (int dt = 0; dt < 8; ++dt)
#pragma unroll
      for (int r = 0; r < 4; ++r) o[dt][r] *= alpha[r];
#pragma unroll
    for (int r = 0; r < 4; ++r) {
      int prow = quad * 4 + r;
#pragma unroll
      for (int nt = 0; nt < 4; ++nt)
        Pl[wave * 1024 + prow * 64 + ((nt * 16 + l16) ^ ((prow & 7) << 3))] = f2bf(s_[nt][r]);
    }

    bfrag pf0 = *(const bfrag*)&Pl[wave * 1024 + l16 * 64 + ((quad)     ^ l7) * 8];
    bfrag pf1 = *(const bfrag*)&Pl[wave * 1024 + l16 * 64 + ((quad + 4) ^ l7) * 8];
#pragma unroll
    for (int dt = 0; dt < 8; ++dt) {
      bfrag vf0 = *(const bfrag*)&Vl[(dt * 16 + l16) * 64 + ((quad)     ^ l7) * 8];
      bfrag vf1 = *(const bfrag*)&Vl[(dt * 16 + l16) * 64 + ((quad + 4) ^ l7) * 8];
      o[dt] = __builtin_amdgcn_mfma_f32_16x16x32_bf16(pf0, vf0, o[dt], 0, 0, 0);
      o[dt] = __builtin_amdgcn_mfma_f32_16x16x32_bf16(pf1, vf1, o[dt], 0, 0, 0);
    }
  }

  float linv[4];
#pragma unroll
  for (int r = 0; r < 4; ++r) linv[r] = 1.0f / l_r[r];
#pragma unroll
  for (int dt = 0; dt < 8; ++dt) {
#pragma unroll
    for (int r = 0; r < 4; ++r) {
      int s = qb + wave * 16 + quad * 4 + r;
      attn[(size_t)s * DM + h * HD + dt * 16 + l16] = f2bf(o[dt][r] * linv[r]);
    }
  }
}

// ---------------- launch ----------------
extern "C" void kernel_launch(void* const* d_in, const int* in_sizes, int n_in,
                              void* d_out, int out_size, void* d_ws, size_t ws_size,
                              hipStream_t stream) {
  const float* image = (const float*)d_in[0];
  const float* text = (const float*)d_in[1];
  const float* img_cos = (const float*)d_in[2];
  const float* img_sin = (const float*)d_in[3];
  const float* txt_cos = (const float*)d_in[4];
  const float* txt_sin = (const float*)d_in[5];
  const float* Wqkv = (const float*)d_in[6];
  const float* bqkv = (const float*)d_in[7];
  const float* Wadd = (const float*)d_in[8];
  const float* badd = (const float*)d_in[9];
  const float* gq = (const float*)d_in[10];
  const float* gk = (const float*)d_in[11];
  const float* gaq = (const float*)d_in[12];
  const float* gak = (const float*)d_in[13];
  const float* Wout = (const float*)d_in[14];
  const float* bout = (const float*)d_in[15];
  const float* Waddout = (const float*)d_in[16];
  const float* baddout = (const float*)d_in[17];

  char* ws = (char*)d_ws;
  size_t off = 0;
  // x_bf: [SALL][DM] bf16, txt rows 0-255 then img rows (matches attention s-order).
  // Dead after QKV GEMM; attn (same size) aliases it.
  unsigned short* x_bf = (unsigned short*)(ws + off); off += (size_t)SALL * DM * 2;        // 14.2 MB
  unsigned short* attn = x_bf;  // alias: [SALL][DM] bf16, written by flash only
  unsigned short* Wqkv_t = (unsigned short*)(ws + off); off += (size_t)DM3 * DM * 2;       // 56.6 MB
  unsigned short* Wadd_t = (unsigned short*)(ws + off); off += (size_t)DM3 * DM * 2;       // 56.6 MB
  unsigned short* Wout_t = (unsigned short*)(ws + off); off += (size_t)DM * DM * 2;        // 18.9 MB
  unsigned short* Waddout_t = (unsigned short*)(ws + off); off += (size_t)DM * DM * 2;     // 18.9 MB
  float* qkvf = (float*)(ws + off); off += (size_t)2 * NH * SALL * HD * 4;                 // 56.6 MB
  unsigned short* Qb = (unsigned short*)(ws + off); off += (size_t)NH * SALL * HD * 2;     // 14.2 MB
  unsigned short* Kb = (unsigned short*)(ws + off); off += (size_t)NH * SALL * HD * 2;     // 14.2 MB
  unsigned short* Vtb = (unsigned short*)(ws + off); off += (size_t)NH * HD * SALL * 2;    // 14.2 MB
  if (off > ws_size) return;

  cast_kernel<<<STXT * DM / 2048, 256, 0, stream>>>(text, x_bf);
  cast_kernel<<<SIMG * DM / 2048, 256, 0, stream>>>(image, x_bf + (size_t)STXT * DM);
  transpose_cast_kernel<<<dim3(DM3 / 64, DM / 64), 256, 0, stream>>>(Wqkv, Wqkv_t, DM, DM3);
  transpose_cast_kernel<<<dim3(DM3 / 64, DM / 64), 256, 0, stream>>>(Wadd, Wadd_t, DM, DM3);
  transpose_cast_kernel<<<dim3(DM / 64, DM / 64), 256, 0, stream>>>(Wout, Wout_t, DM, DM);
  transpose_cast_kernel<<<dim3(DM / 64, DM / 64), 256, 0, stream>>>(Waddout, Waddout_t, DM, DM);

  // merged QKV projection: block-row 0 = txt (Wadd/badd), rest = img (Wqkv/bqkv)
  gemm256<<<dim3((DM3 / 256) * (SALL / 256)), 512, 0, stream>>>(
      x_bf, Wadd_t, Wqkv_t, badd, bqkv, DM3, DM, DM3 / 256, 0, qkvf, Vtb, nullptr, nullptr);

  norm_rope_kernel<<<2 * NH * SALL / 4, 256, 0, stream>>>(qkvf, gq, gk, gaq, gak, img_cos,
                                                          img_sin, txt_cos, txt_sin, Qb, Kb);

  flash_kernel<<<dim3(SALL / 64 * NH), 256, 0, stream>>>(Qb, Kb, Vtb, attn);

  // merged output projection: block-row 0 = txt (Waddout->d_out tail), rest = img (Wout->d_out head)
  gemm256<<<dim3((DM / 256) * (SALL / 256)), 512, 0, stream>>>(
      attn, Waddout_t, Wout_t, baddout, bout, DM, DM, DM / 256, 2, nullptr, nullptr,
      (float*)d_out + (size_t)SIMG * DM, (float*)d_out);
}

// Round 5
// 939.573 us; speedup vs baseline: 1.2159x; 1.0554x over previous
//
#include <hip/hip_runtime.h>

#define NH 24
#define HD 128
#define DM 3072
#define DM3 9216
#define STXT 256
#define SIMG 2048
#define SALL 2304

typedef __attribute__((ext_vector_type(8))) short bfrag;
typedef __attribute__((ext_vector_type(4))) float ffrag;

__device__ __forceinline__ unsigned short f2bf(float f) {
  unsigned int x = __builtin_bit_cast(unsigned int, f);
  x += 0x7fffu + ((x >> 16) & 1u);
  return (unsigned short)(x >> 16);
}

// async 16B global->LDS (DMA). LDS dest = wave-uniform base + lane*16.
__device__ __forceinline__ void gload16(void* lds, const void* g) {
  __builtin_amdgcn_global_load_lds((const __attribute__((address_space(1))) unsigned int*)g,
                                   (__attribute__((address_space(3))) unsigned int*)lds, 16, 0, 0);
}

// ---------------- cast fp32 -> bf16 (8 elems/thread) ----------------
__global__ __launch_bounds__(256) void cast_kernel(const float* __restrict__ in,
                                                   unsigned short* __restrict__ out) {
  int i = blockIdx.x * 256 + threadIdx.x;
  float4 a = ((const float4*)in)[2 * i];
  float4 b = ((const float4*)in)[2 * i + 1];
  uint4 o;
  o.x = (unsigned)f2bf(a.x) | ((unsigned)f2bf(a.y) << 16);
  o.y = (unsigned)f2bf(a.z) | ((unsigned)f2bf(a.w) << 16);
  o.z = (unsigned)f2bf(b.x) | ((unsigned)f2bf(b.y) << 16);
  o.w = (unsigned)f2bf(b.z) | ((unsigned)f2bf(b.w) << 16);
  ((uint4*)out)[i] = o;
}

// ---------------- W [K][N] fp32 -> Wt [N][K] bf16 (64x64 tiles) ----------------
__global__ __launch_bounds__(256) void transpose_cast_kernel(const float* __restrict__ W,
                                                             unsigned short* __restrict__ Wt,
                                                             int K, int N) {
  __shared__ __align__(16) unsigned short tile[64 * 72];  // [n][k], pad 8
  int k0 = blockIdx.y * 64, n0 = blockIdx.x * 64;
  int t = threadIdx.x;
  int rr = t >> 4, cc = (t & 15) * 4;
#pragma unroll
  for (int p = 0; p < 4; ++p) {
    int k = rr + p * 16;
    float4 v = *(const float4*)&W[(size_t)(k0 + k) * N + n0 + cc];
    tile[(cc + 0) * 72 + k] = f2bf(v.x);
    tile[(cc + 1) * 72 + k] = f2bf(v.y);
    tile[(cc + 2) * 72 + k] = f2bf(v.z);
    tile[(cc + 3) * 72 + k] = f2bf(v.w);
  }
  __syncthreads();
  int n = t >> 2, c = (t & 3) * 16;
  float4* dst = (float4*)&Wt[(size_t)(n0 + n) * K + k0 + c];
  dst[0] = *(float4*)&tile[n * 72 + c];
  dst[1] = *(float4*)&tile[n * 72 + c + 8];
}

// ---------------- 256x256 software-pipelined GEMM: C = A[M][K] * Bt[N][K]^T + bias ----
// 512 threads = 8 waves (2 row x 4 col), per-wave C = 128x64, BK=64.
// LDS 128 KiB: 2 bufs x (A 256x64 + B 256x64) as 2 halves of 128x64 bf16 each.
// T2 swizzle (3-bit, verified 0-conflict in R4): linear gload_lds dest +
// pre-swizzled global src chunk; ds_read XORs back (chunk ^ l16&7).
// Schedule (the R4 post-mortem lever): quadrant Gray order (0,0)(0,1)(1,1)(1,0),
// reads for quadrant q+1 issued BEFORE the MFMAs of quadrant q (counted lgkm),
// ONE barrier per K-tile placed after Q3's vmcnt(0) — it certifies both
// (a) all waves' next-buf gloads landed (vmcnt is per-wave) and
// (b) all waves' current-buf ds_reads completed (each wave's lgkm(0) precedes it),
// so STAGE(t+2 -> buf[cur]) at tile end needs no second barrier.
#define STAGE256(tt, c)                                                                          \
  {                                                                                              \
    const size_t kof = (size_t)(tt)*64;                                                          \
    _Pragma("unroll") for (int hf = 0; hf < 2; ++hf) {                                           \
      _Pragma("unroll") for (int i = 0; i < 2; ++i) {                                            \
        gload16(&SA[c][hf][i * 4096 + sdst], Asrc + (size_t)(hf * 128 + i * 64) * K + kof);      \
        gload16(&SB[c][hf][i * 4096 + sdst], Bsrc + (size_t)(hf * 128 + i * 64) * K + kof);      \
      }                                                                                          \
    }                                                                                            \
  }

#define RD_A(DST, AB, QM)                                                                 \
  _Pragma("unroll") for (int mi = 0; mi < 4; ++mi) {                                      \
    DST[mi * 2 + 0] = *(const bfrag*)&(AB)[((QM)*64 + mi * 16 + l16) * 64 + ck0];         \
    DST[mi * 2 + 1] = *(const bfrag*)&(AB)[((QM)*64 + mi * 16 + l16) * 64 + ck1];         \
  }

#define RD_B(DST, BB_, QN)                                                                \
  _Pragma("unroll") for (int ni = 0; ni < 2; ++ni) {                                      \
    DST[ni * 2 + 0] = *(const bfrag*)&(BB_)[((QN)*32 + ni * 16 + l16) * 64 + ck0];        \
    DST[ni * 2 + 1] = *(const bfrag*)&(BB_)[((QN)*32 + ni * 16 + l16) * 64 + ck1];        \
  }

#define MQUAD(QM, QN, AV, BV)                                                             \
  _Pragma("unroll") for (int mi = 0; mi < 4; ++mi) {                                      \
    _Pragma("unroll") for (int ni = 0; ni < 2; ++ni) {                                    \
      _Pragma("unroll") for (int kk = 0; kk < 2; ++kk) {                                  \
        acc[(QM)*4 + mi][(QN)*2 + ni] = __builtin_amdgcn_mfma_f32_16x16x32_bf16(          \
            AV[mi * 2 + kk], BV[ni * 2 + kk], acc[(QM)*4 + mi][(QN)*2 + ni], 0, 0, 0);    \
      }                                                                                   \
    }                                                                                     \
  }

// One K-tile. BAv/BBv swap roles per tile (2x-unrolled caller -> CUR is literal).
#define TILE256(TT, CUR, BAv, BBv)                                                        \
  {                                                                                       \
    const unsigned short* Ab = &SA[CUR][wr][0];                                           \
    const unsigned short* Bb = &SB[CUR][wc >> 1][(wc & 1) * 4096];                        \
    const unsigned short* Abn = &SA[(CUR) ^ 1][wr][0];                                    \
    const unsigned short* Bbn = &SB[(CUR) ^ 1][wc >> 1][(wc & 1) * 4096];                 \
    /* Q1: a0 x bA ; prefetch bB (lands under MFMAs) */                                   \
    asm volatile("s_waitcnt lgkmcnt(0)" ::: "memory"); /* a0,bA in */                     \
    __builtin_amdgcn_sched_barrier(0);                                                    \
    RD_B(BBv, Bb, 1);                                                                     \
    __builtin_amdgcn_s_setprio(1);                                                        \
    MQUAD(0, 0, a0_, BAv);                                                                \
    __builtin_amdgcn_s_setprio(0);                                                        \
    /* Q2: a0 x bB ; prefetch a1 */                                                       \
    asm volatile("s_waitcnt lgkmcnt(0)" ::: "memory"); /* bB in */                        \
    __builtin_amdgcn_sched_barrier(0);                                                    \
    RD_A(a1_, Ab, 1);                                                                     \
    __builtin_amdgcn_s_setprio(1);                                                        \
    MQUAD(0, 1, a0_, BBv);                                                                \
    __builtin_amdgcn_s_setprio(0);                                                        \
    /* Q3: a1 x bB ; vmcnt+barrier then next-tile a0 prefetch */                          \
    asm volatile("s_waitcnt lgkmcnt(0)" ::: "memory"); /* a1 in */                        \
    __builtin_amdgcn_sched_barrier(0);                                                    \
    if ((TT) + 1 < NT) {                                                                  \
      asm volatile("s_waitcnt vmcnt(0)" ::: "memory"); /* my next-buf loads in */         \
      __builtin_amdgcn_s_barrier();                    /* everyone's in + cur reads done */\
      RD_A(a0_, Abn, 0);                                                                  \
    }                                                                                     \
    __builtin_amdgcn_s_setprio(1);                                                        \
    MQUAD(1, 1, a1_, BBv);                                                                \
    __builtin_amdgcn_s_setprio(0);                                                        \
    /* Q4: a1 x bA ; next-tile bA -> BBv slots (free after Q3) */                         \
    if ((TT) + 1 < NT) RD_B(BBv, Bbn, 0);                                                 \
    __builtin_amdgcn_s_setprio(1);                                                        \
    MQUAD(1, 0, a1_, BAv);                                                                \
    __builtin_amdgcn_s_setprio(0);                                                        \
    if ((TT) + 2 < NT) STAGE256((TT) + 2, CUR);                                           \
  }

__global__ __launch_bounds__(512, 2) void gemm256(const unsigned short* __restrict__ A,
                                                  const unsigned short* __restrict__ Bt_txt,
                                                  const unsigned short* __restrict__ Bt_img,
                                                  const float* __restrict__ bias_txt,
                                                  const float* __restrict__ bias_img,
                                                  int N, int K, int ncols, int mode,
                                                  float* __restrict__ qkvf,
                                                  unsigned short* __restrict__ vtb,
                                                  float* __restrict__ out_txt,
                                                  float* __restrict__ out_img) {
  __shared__ __align__(16) unsigned short SA[2][2][8192];
  __shared__ __align__(16) unsigned short SB[2][2][8192];
  const int tid = threadIdx.x;
  const int wave = tid >> 6, lane = tid & 63, quad = lane >> 4, l16 = lane & 15;
  const int wr = wave >> 2, wc = wave & 3;
  // XCD-chunked bijective block swizzle (m204), row-major tile order
  const int nwg = gridDim.x;
  const int q8 = nwg >> 3, r8 = nwg & 7;
  const int xcd = blockIdx.x & 7, idx = blockIdx.x >> 3;
  const int wg = (xcd < r8 ? xcd * (q8 + 1) : r8 * (q8 + 1) + (xcd - r8) * q8) + idx;
  const int m0 = (wg / ncols) * 256, n0 = (wg % ncols) * 256;
  const unsigned short* Bt = (m0 == 0) ? Bt_txt : Bt_img;
  const float* bias = (m0 == 0) ? bias_txt : bias_img;

  // staging map: thread -> row wave*8 + lane/8 (per 64-row issue region), chunk lane%8.
  // full 3-bit pre-swizzle on the SOURCE chunk; LDS dest linear (gload_lds req).
  const int srow = wave * 8 + (lane >> 3);
  const int scs = ((lane & 7) ^ (srow & 7)) * 8;
  const int sdst = wave * 512 + lane * 8;
  const unsigned short* Asrc = A + (size_t)(m0 + srow) * K + scs;
  const unsigned short* Bsrc = Bt + (size_t)(n0 + srow) * K + scs;

  // read-side swizzle: all frag rows == l16 (mod 8)
  const int rsw = l16 & 7;
  const int ck0 = (quad ^ rsw) * 8;
  const int ck1 = ((quad + 4) ^ rsw) * 8;

  ffrag zf = {0.f, 0.f, 0.f, 0.f};
  ffrag acc[8][4];
#pragma unroll
  for (int i = 0; i < 8; ++i)
#pragma unroll
    for (int j = 0; j < 4; ++j) acc[i][j] = zf;

  const int NT = K >> 6;  // even (K=3072 -> 48)
  bfrag a0_[8], a1_[8], bX[4], bY[4];

  // prologue: stage tiles 0,1; wait tile0 (per-wave) + barrier (all waves); first reads
  STAGE256(0, 0);
  STAGE256(1, 1);
  asm volatile("s_waitcnt vmcnt(8)" ::: "memory");
  __builtin_amdgcn_s_barrier();
  {
    const unsigned short* Ab0 = &SA[0][wr][0];
    const unsigned short* Bb0 = &SB[0][wc >> 1][(wc & 1) * 4096];
    RD_A(a0_, Ab0, 0);
    RD_B(bX, Bb0, 0);
  }

  for (int t = 0; t < NT; t += 2) {
    TILE256(t, 0, bX, bY);
    TILE256(t + 1, 1, bY, bX);
  }

  // epilogue
#pragma unroll
  for (int a = 0; a < 8; ++a) {
    const int rowb = m0 + wr * 128 + (a >> 2) * 64 + (a & 3) * 16 + quad * 4;
#pragma unroll
    for (int b = 0; b < 4; ++b) {
      const int gn = n0 + wc * 64 + (b >> 1) * 32 + (b & 1) * 16 + l16;
      const float bv = bias[gn];
#pragma unroll
      for (int r = 0; r < 4; ++r) {
        float v = acc[a][b][r] + bv;
        int gm = rowb + r;
        if (mode == 2) {
          if (gm < STXT)
            out_txt[(size_t)gm * N + gn] = v;
          else
            out_img[(size_t)(gm - STXT) * N + gn] = v;
        } else {
          int which = gn / DM;
          int rr2 = gn - which * DM;
          int head = rr2 >> 7, d = rr2 & 127;
          if (which < 2)
            qkvf[(((size_t)which * NH + head) * SALL + gm) * HD + d] = v;
          else
            vtb[((size_t)head * HD + d) * SALL + gm] = f2bf(v);
        }
      }
    }
  }
}

// ---------------- fused RMSNorm + RoPE on q,k ----------------
__global__ __launch_bounds__(256) void norm_rope_kernel(
    const float* __restrict__ qkvf, const float* __restrict__ gq, const float* __restrict__ gk,
    const float* __restrict__ gaq, const float* __restrict__ gak,
    const float* __restrict__ img_cos, const float* __restrict__ img_sin,
    const float* __restrict__ txt_cos, const float* __restrict__ txt_sin,
    unsigned short* __restrict__ Qb, unsigned short* __restrict__ Kb) {
  int wave = threadIdx.x >> 6, lane = threadIdx.x & 63;
  int row = blockIdx.x * 4 + wave;  // < 2*NH*SALL
  int which = row / (NH * SALL);
  int rem = row - which * (NH * SALL);
  int s = rem % SALL;
  float2 v = *(const float2*)&qkvf[(size_t)row * HD + lane * 2];
  float ss = v.x * v.x + v.y * v.y;
#pragma unroll
  for (int m = 1; m < 64; m <<= 1) ss += __shfl_xor(ss, m);
  float rinv = rsqrtf(ss * (1.0f / 128.0f) + 1e-6f);
  bool is_txt = s < STXT;
  int pos = is_txt ? s : s - STXT;
  const float* g = (which == 0) ? (is_txt ? gaq : gq) : (is_txt ? gak : gk);
  const float* ct = is_txt ? txt_cos : img_cos;
  const float* st = is_txt ? txt_sin : img_sin;
  float c = ct[pos * 64 + lane], sn = st[pos * 64 + lane];
  float x0 = v.x * rinv * g[lane * 2];
  float x1 = v.y * rinv * g[lane * 2 + 1];
  float o0 = x0 * c - x1 * sn;
  float o1 = x0 * sn + x1 * c;
  unsigned short* out = (which == 0 ? Qb : Kb) + (size_t)rem * HD + lane * 2;
  *(unsigned int*)out = (unsigned)f2bf(o0) | ((unsigned)f2bf(o1) << 16);
}

// ---------------- flash attention (unchanged from R2) ----------------
__global__ __launch_bounds__(256) void flash_kernel(const unsigned short* __restrict__ Q,
                                                    const unsigned short* __restrict__ Kg,
                                                    const unsigned short* __restrict__ Vt,
                                                    unsigned short* __restrict__ attn) {
  __shared__ __align__(16) unsigned short Kl[64 * 128];    // 16 KB, swizzled
  __shared__ __align__(16) unsigned short Vl[128 * 64];    // 16 KB, swizzled
  __shared__ __align__(16) unsigned short Pl[4 * 16 * 64]; // 8 KB, per-wave, swizzled
  // bijective chunked XCD swizzle: 864 = 8 * 108, 108 = 3 heads * 36 q-blocks
  int bid = blockIdx.x;
  int g = (bid & 7) * 108 + (bid >> 3);
  const int h = g / 36;
  const int qb = (g - h * 36) * 64;
  const int tid = threadIdx.x;
  const int wave = tid >> 6, lane = tid & 63, quad = lane >> 4, l16 = lane & 15;
  const int l7 = l16 & 7;

  const unsigned short* qrow = Q + ((size_t)h * SALL + qb + wave * 16 + l16) * HD;
  bfrag aq[4];
#pragma unroll
  for (int kk = 0; kk < 4; ++kk) aq[kk] = *(const bfrag*)&qrow[kk * 32 + quad * 8];

  const unsigned short* Kh = Kg + (size_t)h * SALL * HD;
  const unsigned short* Vh = Vt + (size_t)h * HD * SALL;

  const int kr = tid >> 4, kc = tid & 15;
  const int vr = tid >> 3, vc = tid & 7;
  const int kswz = kc ^ (kr & 7);
  const int vswz = vc ^ (vr & 7);

  ffrag zf = {0.f, 0.f, 0.f, 0.f};
  ffrag o[8];
#pragma unroll
  for (int i = 0; i < 8; ++i) o[i] = zf;
  float m_r[4] = {-__builtin_inff(), -__builtin_inff(), -__builtin_inff(), -__builtin_inff()};
  float l_r[4] = {0.f, 0.f, 0.f, 0.f};
  const float sc = 0.08838834764831845f * 1.4426950408889634f;  // 1/sqrt(128) * log2(e)

  bfrag kreg[4], vreg[4];
#pragma unroll
  for (int p = 0; p < 4; ++p) {
    kreg[p] = *(const bfrag*)&Kh[(size_t)(kr + p * 16) * HD + kc * 8];
    vreg[p] = *(const bfrag*)&Vh[(size_t)(vr + p * 32) * SALL + vc * 8];
  }

  for (int t = 0; t < SALL / 64; ++t) {
    __syncthreads();
#pragma unroll
    for (int p = 0; p < 4; ++p) {
      *(bfrag*)&Kl[(kr + p * 16) * 128 + kswz * 8] = kreg[p];
      *(bfrag*)&Vl[(vr + p * 32) * 64 + vswz * 8] = vreg[p];
    }
    __syncthreads();

    if (t + 1 < SALL / 64) {
      int kn = (t + 1) * 64;
#pragma unroll
      for (int p = 0; p < 4; ++p) {
        kreg[p] = *(const bfrag*)&Kh[(size_t)(kn + kr + p * 16) * HD + kc * 8];
        vreg[p] = *(const bfrag*)&Vh[(size_t)(vr + p * 32) * SALL + kn + vc * 8];
      }
    }

    ffrag s_[4];
#pragma unroll
    for (int nt = 0; nt < 4; ++nt) s_[nt] = zf;
#pragma unroll
    for (int kk = 0; kk < 4; ++kk) {
#pragma unroll
      for (int nt = 0; nt < 4; ++nt) {
        bfrag kf = *(const bfrag*)&Kl[(nt * 16 + l16) * 128 + ((kk * 4 + quad) ^ l7) * 8];
        s_[nt] = __builtin_amdgcn_mfma_f32_16x16x32_bf16(aq[kk], kf, s_[nt], 0, 0, 0);
      }
    }
#pragma unroll
    for (int nt = 0; nt < 4; ++nt)
#pragma unroll
      for (int r = 0; r < 4; ++r) s_[nt][r] *= sc;

    float alpha[4];
#pragma unroll
    for (int r = 0; r < 4; ++r) {
      float mx = fmaxf(fmaxf(s_[0][r], s_[1][r]), fmaxf(s_[2][r], s_[3][r]));
#pragma unroll
      for (int msk = 1; msk < 16; msk <<= 1) mx = fmaxf(mx, __shfl_xor(mx, msk));
      float mnew = fmaxf(m_r[r], mx);
      alpha[r] = exp2f(m_r[r] - mnew);
      m_r[r] = mnew;
      float rs = 0.f;
#pragma unroll
      for (int nt = 0; nt < 4; ++nt) {
        float p = exp2f(s_[nt][r] - mnew);
        s_[nt][r] = p;
        rs += p;
      }
#pragma unroll
      for (int msk = 1; msk < 16; msk <<= 1) rs += __shfl_xor(rs, msk);
      l_r[r] = l_r[r] * alpha[r] + rs;
    }
#pragma unroll
    for (int dt = 0; dt < 8; ++dt)
#pragma unroll
      for (int r = 0; r < 4; ++r) o[dt][r] *= alpha[r];
#pragma unroll
    for (int r = 0; r < 4; ++r) {
      int prow = quad * 4 + r;
#pragma unroll
      for (int nt = 0; nt < 4; ++nt)
        Pl[wave * 1024 + prow * 64 + ((nt * 16 + l16) ^ ((prow & 7) << 3))] = f2bf(s_[nt][r]);
    }

    bfrag pf0 = *(const bfrag*)&Pl[wave * 1024 + l16 * 64 + ((quad)     ^ l7) * 8];
    bfrag pf1 = *(const bfrag*)&Pl[wave * 1024 + l16 * 64 + ((quad + 4) ^ l7) * 8];
#pragma unroll
    for (int dt = 0; dt < 8; ++dt) {
      bfrag vf0 = *(const bfrag*)&Vl[(dt * 16 + l16) * 64 + ((quad)     ^ l7) * 8];
      bfrag vf1 = *(const bfrag*)&Vl[(dt * 16 + l16) * 64 + ((quad + 4) ^ l7) * 8];
      o[dt] = __builtin_amdgcn_mfma_f32_16x16x32_bf16(pf0, vf0, o[dt], 0, 0, 0);
      o[dt] = __builtin_amdgcn_mfma_f32_16x16x32_bf16(pf1, vf1, o[dt], 0, 0, 0);
    }
  }

  float linv[4];
#pragma unroll
  for (int r = 0; r < 4; ++r) linv[r] = 1.0f / l_r[r];
#pragma unroll
  for (int dt = 0; dt < 8; ++dt) {
#pragma unroll
    for (int r = 0; r < 4; ++r) {
      int s = qb + wave * 16 + quad * 4 + r;
      attn[(size_t)s * DM + h * HD + dt * 16 + l16] = f2bf(o[dt][r] * linv[r]);
    }
  }
}

// ---------------- launch ----------------
extern "C" void kernel_launch(void* const* d_in, const int* in_sizes, int n_in,
                              void* d_out, int out_size, void* d_ws, size_t ws_size,
                              hipStream_t stream) {
  const float* image = (const float*)d_in[0];
  const float* text = (const float*)d_in[1];
  const float* img_cos = (const float*)d_in[2];
  const float* img_sin = (const float*)d_in[3];
  const float* txt_cos = (const float*)d_in[4];
  const float* txt_sin = (const float*)d_in[5];
  const float* Wqkv = (const float*)d_in[6];
  const float* bqkv = (const float*)d_in[7];
  const float* Wadd = (const float*)d_in[8];
  const float* badd = (const float*)d_in[9];
  const float* gq = (const float*)d_in[10];
  const float* gk = (const float*)d_in[11];
  const float* gaq = (const float*)d_in[12];
  const float* gak = (const float*)d_in[13];
  const float* Wout = (const float*)d_in[14];
  const float* bout = (const float*)d_in[15];
  const float* Waddout = (const float*)d_in[16];
  const float* baddout = (const float*)d_in[17];

  char* ws = (char*)d_ws;
  size_t off = 0;
  // x_bf: [SALL][DM] bf16, txt rows 0-255 then img rows (matches attention s-order).
  // Dead after QKV GEMM; attn (same size) aliases it.
  unsigned short* x_bf = (unsigned short*)(ws + off); off += (size_t)SALL * DM * 2;        // 14.2 MB
  unsigned short* attn = x_bf;  // alias: [SALL][DM] bf16, written by flash only
  unsigned short* Wqkv_t = (unsigned short*)(ws + off); off += (size_t)DM3 * DM * 2;       // 56.6 MB
  unsigned short* Wadd_t = (unsigned short*)(ws + off); off += (size_t)DM3 * DM * 2;       // 56.6 MB
  unsigned short* Wout_t = (unsigned short*)(ws + off); off += (size_t)DM * DM * 2;        // 18.9 MB
  unsigned short* Waddout_t = (unsigned short*)(ws + off); off += (size_t)DM * DM * 2;     // 18.9 MB
  float* qkvf = (float*)(ws + off); off += (size_t)2 * NH * SALL * HD * 4;                 // 56.6 MB
  unsigned short* Qb = (unsigned short*)(ws + off); off += (size_t)NH * SALL * HD * 2;     // 14.2 MB
  unsigned short* Kb = (unsigned short*)(ws + off); off += (size_t)NH * SALL * HD * 2;     // 14.2 MB
  unsigned short* Vtb = (unsigned short*)(ws + off); off += (size_t)NH * HD * SALL * 2;    // 14.2 MB
  if (off > ws_size) return;

  cast_kernel<<<STXT * DM / 2048, 256, 0, stream>>>(text, x_bf);
  cast_kernel<<<SIMG * DM / 2048, 256, 0, stream>>>(image, x_bf + (size_t)STXT * DM);
  transpose_cast_kernel<<<dim3(DM3 / 64, DM / 64), 256, 0, stream>>>(Wqkv, Wqkv_t, DM, DM3);
  transpose_cast_kernel<<<dim3(DM3 / 64, DM / 64), 256, 0, stream>>>(Wadd, Wadd_t, DM, DM3);
  transpose_cast_kernel<<<dim3(DM / 64, DM / 64), 256, 0, stream>>>(Wout, Wout_t, DM, DM);
  transpose_cast_kernel<<<dim3(DM / 64, DM / 64), 256, 0, stream>>>(Waddout, Waddout_t, DM, DM);

  // merged QKV projection: block-row 0 = txt (Wadd/badd), rest = img (Wqkv/bqkv)
  gemm256<<<dim3((DM3 / 256) * (SALL / 256)), 512, 0, stream>>>(
      x_bf, Wadd_t, Wqkv_t, badd, bqkv, DM3, DM, DM3 / 256, 0, qkvf, Vtb, nullptr, nullptr);

  norm_rope_kernel<<<2 * NH * SALL / 4, 256, 0, stream>>>(qkvf, gq, gk, gaq, gak, img_cos,
                                                          img_sin, txt_cos, txt_sin, Qb, Kb);

  flash_kernel<<<dim3(SALL / 64 * NH), 256, 0, stream>>>(Qb, Kb, Vtb, attn);

  // merged output projection: block-row 0 = txt (Waddout->d_out tail), rest = img (Wout->d_out head)
  gemm256<<<dim3((DM / 256) * (SALL / 256)), 512, 0, stream>>>(
      attn, Waddout_t, Wout_t, baddout, bout, DM, DM, DM / 256, 2, nullptr, nullptr,
      (float*)d_out + (size_t)SIMG * DM, (float*)d_out);
}

// Round 6
// 863.010 us; speedup vs baseline: 1.3238x; 1.0887x over previous
//
#include <hip/hip_runtime.h>

#define NH 24
#define HD 128
#define DM 3072
#define DM3 9216
#define STXT 256
#define SIMG 2048
#define SALL 2304

typedef __attribute__((ext_vector_type(8))) short bfrag;
typedef __attribute__((ext_vector_type(4))) float ffrag;

__device__ __forceinline__ unsigned short f2bf(float f) {
  unsigned int x = __builtin_bit_cast(unsigned int, f);
  x += 0x7fffu + ((x >> 16) & 1u);
  return (unsigned short)(x >> 16);
}

// async 16B global->LDS (DMA). LDS dest = wave-uniform base + lane*16.
__device__ __forceinline__ void gload16(void* lds, const void* g) {
  __builtin_amdgcn_global_load_lds((const __attribute__((address_space(1))) unsigned int*)g,
                                   (__attribute__((address_space(3))) unsigned int*)lds, 16, 0, 0);
}

// ---------------- cast fp32 -> bf16 (8 elems/thread) ----------------
__global__ __launch_bounds__(256) void cast_kernel(const float* __restrict__ in,
                                                   unsigned short* __restrict__ out) {
  int i = blockIdx.x * 256 + threadIdx.x;
  float4 a = ((const float4*)in)[2 * i];
  float4 b = ((const float4*)in)[2 * i + 1];
  uint4 o;
  o.x = (unsigned)f2bf(a.x) | ((unsigned)f2bf(a.y) << 16);
  o.y = (unsigned)f2bf(a.z) | ((unsigned)f2bf(a.w) << 16);
  o.z = (unsigned)f2bf(b.x) | ((unsigned)f2bf(b.y) << 16);
  o.w = (unsigned)f2bf(b.z) | ((unsigned)f2bf(b.w) << 16);
  ((uint4*)out)[i] = o;
}

// ---------------- W [K][N] fp32 -> Wt [N][K] bf16 (64x64 tiles) ----------------
__global__ __launch_bounds__(256) void transpose_cast_kernel(const float* __restrict__ W,
                                                             unsigned short* __restrict__ Wt,
                                                             int K, int N) {
  __shared__ __align__(16) unsigned short tile[64 * 72];  // [n][k], pad 8
  int k0 = blockIdx.y * 64, n0 = blockIdx.x * 64;
  int t = threadIdx.x;
  int rr = t >> 4, cc = (t & 15) * 4;
#pragma unroll
  for (int p = 0; p < 4; ++p) {
    int k = rr + p * 16;
    float4 v = *(const float4*)&W[(size_t)(k0 + k) * N + n0 + cc];
    tile[(cc + 0) * 72 + k] = f2bf(v.x);
    tile[(cc + 1) * 72 + k] = f2bf(v.y);
    tile[(cc + 2) * 72 + k] = f2bf(v.z);
    tile[(cc + 3) * 72 + k] = f2bf(v.w);
  }
  __syncthreads();
  int n = t >> 2, c = (t & 3) * 16;
  float4* dst = (float4*)&Wt[(size_t)(n0 + n) * K + k0 + c];
  dst[0] = *(float4*)&tile[n * 72 + c];
  dst[1] = *(float4*)&tile[n * 72 + c + 8];
}

// ---------------- 128x128 2-phase GEMM: C = A[M][K] * Bt[N][K]^T + bias ----------------
// m97 structure (proven 513 TF at this shape in R2) + T3 minimum-2-phase pipeline:
// STAGE(t+1 -> buf^1) issued BEFORE compute of tile t; ONE __syncthreads per tile.
// Its vmcnt(0)+lgkm(0) drain then lands a full compute-phase after load issue
// (vs m97's issue-then-immediately-drain ~20% stall), and 5-6 blocks/CU of TLP
// hide the remainder. LDS 32 KB double-buffered, BK=32, 256 threads, 4 waves.
// Hazards: STAGE(t+1 -> buf^1) at top of tile t is safe because all waves finished
// reading buf^1 during tile t-1, before tile t-1's closing __syncthreads.
// Merged row-region variant: m0 < STXT -> txt weights/bias, else img.
// mode 0: QKV scatter epilogue (q,k fp32 + v bf16 transposed); mode 2: fp32 rows split.
#define STG128(TT, CB)                                                    \
  {                                                                       \
    const size_t kof = (size_t)(TT)*32;                                   \
    gload16(&As[CB][sr * 32 + sc], Ag + kof);                             \
    gload16(&As[CB][(sr + 64) * 32 + sc], Ag + (size_t)64 * K + kof);     \
    gload16(&Bs[CB][sr * 32 + sc], Bg + kof);                             \
    gload16(&Bs[CB][(sr + 64) * 32 + sc], Bg + (size_t)64 * K + kof);     \
  }

#define TILE128(TT, CB)                                                               \
  {                                                                                   \
    if ((TT) + 1 < NT) STG128((TT) + 1, (CB) ^ 1);                                    \
    bfrag af[4], bfv[4];                                                              \
    _Pragma("unroll") for (int mt = 0; mt < 4; ++mt)                                  \
        af[mt] = *(const bfrag*)&As[CB][(wm + mt * 16 + l16) * 32 + quad * 8];        \
    _Pragma("unroll") for (int nt = 0; nt < 4; ++nt)                                  \
        bfv[nt] = *(const bfrag*)&Bs[CB][(wn + nt * 16 + l16) * 32 + quad * 8];       \
    _Pragma("unroll") for (int mt = 0; mt < 4; ++mt)                                  \
        _Pragma("unroll") for (int nt = 0; nt < 4; ++nt)                              \
            acc[mt][nt] =                                                             \
                __builtin_amdgcn_mfma_f32_16x16x32_bf16(af[mt], bfv[nt], acc[mt][nt], \
                                                        0, 0, 0);                     \
    __syncthreads();                                                                  \
  }

__global__ __launch_bounds__(256) void gemm128(const unsigned short* __restrict__ A,
                                               const unsigned short* __restrict__ Bt_txt,
                                               const unsigned short* __restrict__ Bt_img,
                                               const float* __restrict__ bias_txt,
                                               const float* __restrict__ bias_img,
                                               int N, int K, int ncols, int mode,
                                               float* __restrict__ qkvf,
                                               unsigned short* __restrict__ vtb,
                                               float* __restrict__ out_txt,
                                               float* __restrict__ out_img) {
  __shared__ __align__(16) unsigned short As[2][128 * 32];
  __shared__ __align__(16) unsigned short Bs[2][128 * 32];
  const int tid = threadIdx.x;
  const int wave = tid >> 6, lane = tid & 63, quad = lane >> 4, l16 = lane & 15;
  const int wm = (wave >> 1) * 64, wn = (wave & 1) * 64;
  // XCD-chunked bijective block swizzle (m204), row-major tile order (A-panel L2 reuse)
  const int nwg = gridDim.x;
  const int q8 = nwg >> 3, r8 = nwg & 7;
  const int xcd = blockIdx.x & 7, idx = blockIdx.x >> 3;
  const int wg = (xcd < r8 ? xcd * (q8 + 1) : r8 * (q8 + 1) + (xcd - r8) * q8) + idx;
  const int m0 = (wg / ncols) * 128, n0 = (wg % ncols) * 128;
  const unsigned short* Bt = (m0 < STXT) ? Bt_txt : Bt_img;
  const float* bias = (m0 < STXT) ? bias_txt : bias_img;

  ffrag zf = {0.f, 0.f, 0.f, 0.f};
  ffrag acc[4][4];
#pragma unroll
  for (int i = 0; i < 4; ++i)
#pragma unroll
    for (int j = 0; j < 4; ++j) acc[i][j] = zf;

  // staging map: thread t -> row t>>2 (0..63), 16B chunk t&3; per-wave dest = base + lane*16.
  const int sr = tid >> 2;
  const int sc = (tid & 3) * 8;
  const unsigned short* Ag = A + (size_t)(m0 + sr) * K + sc;
  const unsigned short* Bg = Bt + (size_t)(n0 + sr) * K + sc;

  const int NT = K >> 5;  // K=3072 -> 96 (even)
  STG128(0, 0);
  __syncthreads();  // drains prologue loads, all waves aligned
  for (int t = 0; t < NT; t += 2) {
    TILE128(t, 0);
    TILE128(t + 1, 1);
  }

  float bv[4];
#pragma unroll
  for (int nt = 0; nt < 4; ++nt) bv[nt] = bias[n0 + wn + nt * 16 + l16];

#pragma unroll
  for (int mt = 0; mt < 4; ++mt) {
#pragma unroll
    for (int nt = 0; nt < 4; ++nt) {
      int gn = (int)n0 + wn + nt * 16 + l16;
#pragma unroll
      for (int r = 0; r < 4; ++r) {
        float v = acc[mt][nt][r] + bv[nt];
        int gm = (int)m0 + wm + mt * 16 + quad * 4 + r;
        if (mode == 2) {
          if (gm < STXT)
            out_txt[(size_t)gm * N + gn] = v;
          else
            out_img[(size_t)(gm - STXT) * N + gn] = v;
        } else {
          int which = gn / DM;
          int rr2 = gn - which * DM;
          int head = rr2 >> 7, d = rr2 & 127;
          if (which < 2)
            qkvf[(((size_t)which * NH + head) * SALL + gm) * HD + d] = v;
          else
            vtb[((size_t)head * HD + d) * SALL + gm] = f2bf(v);
        }
      }
    }
  }
}

// ---------------- fused RMSNorm + RoPE on q,k ----------------
__global__ __launch_bounds__(256) void norm_rope_kernel(
    const float* __restrict__ qkvf, const float* __restrict__ gq, const float* __restrict__ gk,
    const float* __restrict__ gaq, const float* __restrict__ gak,
    const float* __restrict__ img_cos, const float* __restrict__ img_sin,
    const float* __restrict__ txt_cos, const float* __restrict__ txt_sin,
    unsigned short* __restrict__ Qb, unsigned short* __restrict__ Kb) {
  int wave = threadIdx.x >> 6, lane = threadIdx.x & 63;
  int row = blockIdx.x * 4 + wave;  // < 2*NH*SALL
  int which = row / (NH * SALL);
  int rem = row - which * (NH * SALL);
  int s = rem % SALL;
  float2 v = *(const float2*)&qkvf[(size_t)row * HD + lane * 2];
  float ss = v.x * v.x + v.y * v.y;
#pragma unroll
  for (int m = 1; m < 64; m <<= 1) ss += __shfl_xor(ss, m);
  float rinv = rsqrtf(ss * (1.0f / 128.0f) + 1e-6f);
  bool is_txt = s < STXT;
  int pos = is_txt ? s : s - STXT;
  const float* g = (which == 0) ? (is_txt ? gaq : gq) : (is_txt ? gak : gk);
  const float* ct = is_txt ? txt_cos : img_cos;
  const float* st = is_txt ? txt_sin : img_sin;
  float c = ct[pos * 64 + lane], sn = st[pos * 64 + lane];
  float x0 = v.x * rinv * g[lane * 2];
  float x1 = v.y * rinv * g[lane * 2 + 1];
  float o0 = x0 * c - x1 * sn;
  float o1 = x0 * sn + x1 * c;
  unsigned short* out = (which == 0 ? Qb : Kb) + (size_t)rem * HD + lane * 2;
  *(unsigned int*)out = (unsigned)f2bf(o0) | ((unsigned)f2bf(o1) << 16);
}

// ---------------- flash attention (unchanged from R2) ----------------
__global__ __launch_bounds__(256) void flash_kernel(const unsigned short* __restrict__ Q,
                                                    const unsigned short* __restrict__ Kg,
                                                    const unsigned short* __restrict__ Vt,
                                                    unsigned short* __restrict__ attn) {
  __shared__ __align__(16) unsigned short Kl[64 * 128];    // 16 KB, swizzled
  __shared__ __align__(16) unsigned short Vl[128 * 64];    // 16 KB, swizzled
  __shared__ __align__(16) unsigned short Pl[4 * 16 * 64]; // 8 KB, per-wave, swizzled
  // bijective chunked XCD swizzle: 864 = 8 * 108, 108 = 3 heads * 36 q-blocks
  int bid = blockIdx.x;
  int g = (bid & 7) * 108 + (bid >> 3);
  const int h = g / 36;
  const int qb = (g - h * 36) * 64;
  const int tid = threadIdx.x;
  const int wave = tid >> 6, lane = tid & 63, quad = lane >> 4, l16 = lane & 15;
  const int l7 = l16 & 7;

  const unsigned short* qrow = Q + ((size_t)h * SALL + qb + wave * 16 + l16) * HD;
  bfrag aq[4];
#pragma unroll
  for (int kk = 0; kk < 4; ++kk) aq[kk] = *(const bfrag*)&qrow[kk * 32 + quad * 8];

  const unsigned short* Kh = Kg + (size_t)h * SALL * HD;
  const unsigned short* Vh = Vt + (size_t)h * HD * SALL;

  const int kr = tid >> 4, kc = tid & 15;
  const int vr = tid >> 3, vc = tid & 7;
  const int kswz = kc ^ (kr & 7);
  const int vswz = vc ^ (vr & 7);

  ffrag zf = {0.f, 0.f, 0.f, 0.f};
  ffrag o[8];
#pragma unroll
  for (int i = 0; i < 8; ++i) o[i] = zf;
  float m_r[4] = {-__builtin_inff(), -__builtin_inff(), -__builtin_inff(), -__builtin_inff()};
  float l_r[4] = {0.f, 0.f, 0.f, 0.f};
  const float sc = 0.08838834764831845f * 1.4426950408889634f;  // 1/sqrt(128) * log2(e)

  bfrag kreg[4], vreg[4];
#pragma unroll
  for (int p = 0; p < 4; ++p) {
    kreg[p] = *(const bfrag*)&Kh[(size_t)(kr + p * 16) * HD + kc * 8];
    vreg[p] = *(const bfrag*)&Vh[(size_t)(vr + p * 32) * SALL + vc * 8];
  }

  for (int t = 0; t < SALL / 64; ++t) {
    __syncthreads();
#pragma unroll
    for (int p = 0; p < 4; ++p) {
      *(bfrag*)&Kl[(kr + p * 16) * 128 + kswz * 8] = kreg[p];
      *(bfrag*)&Vl[(vr + p * 32) * 64 + vswz * 8] = vreg[p];
    }
    __syncthreads();

    if (t + 1 < SALL / 64) {
      int kn = (t + 1) * 64;
#pragma unroll
      for (int p = 0; p < 4; ++p) {
        kreg[p] = *(const bfrag*)&Kh[(size_t)(kn + kr + p * 16) * HD + kc * 8];
        vreg[p] = *(const bfrag*)&Vh[(size_t)(vr + p * 32) * SALL + kn + vc * 8];
      }
    }

    ffrag s_[4];
#pragma unroll
    for (int nt = 0; nt < 4; ++nt) s_[nt] = zf;
#pragma unroll
    for (int kk = 0; kk < 4; ++kk) {
#pragma unroll
      for (int nt = 0; nt < 4; ++nt) {
        bfrag kf = *(const bfrag*)&Kl[(nt * 16 + l16) * 128 + ((kk * 4 + quad) ^ l7) * 8];
        s_[nt] = __builtin_amdgcn_mfma_f32_16x16x32_bf16(aq[kk], kf, s_[nt], 0, 0, 0);
      }
    }
#pragma unroll
    for (int nt = 0; nt < 4; ++nt)
#pragma unroll
      for (int r = 0; r < 4; ++r) s_[nt][r] *= sc;

    float alpha[4];
#pragma unroll
    for (int r = 0; r < 4; ++r) {
      float mx = fmaxf(fmaxf(s_[0][r], s_[1][r]), fmaxf(s_[2][r], s_[3][r]));
#pragma unroll
      for (int msk = 1; msk < 16; msk <<= 1) mx = fmaxf(mx, __shfl_xor(mx, msk));
      float mnew = fmaxf(m_r[r], mx);
      alpha[r] = exp2f(m_r[r] - mnew);
      m_r[r] = mnew;
      float rs = 0.f;
#pragma unroll
      for (int nt = 0; nt < 4; ++nt) {
        float p = exp2f(s_[nt][r] - mnew);
        s_[nt][r] = p;
        rs += p;
      }
#pragma unroll
      for (int msk = 1; msk < 16; msk <<= 1) rs += __shfl_xor(rs, msk);
      l_r[r] = l_r[r] * alpha[r] + rs;
    }
#pragma unroll
    for (int dt = 0; dt < 8; ++dt)
#pragma unroll
      for (int r = 0; r < 4; ++r) o[dt][r] *= alpha[r];
#pragma unroll
    for (int r = 0; r < 4; ++r) {
      int prow = quad * 4 + r;
#pragma unroll
      for (int nt = 0; nt < 4; ++nt)
        Pl[wave * 1024 + prow * 64 + ((nt * 16 + l16) ^ ((prow & 7) << 3))] = f2bf(s_[nt][r]);
    }

    bfrag pf0 = *(const bfrag*)&Pl[wave * 1024 + l16 * 64 + ((quad)     ^ l7) * 8];
    bfrag pf1 = *(const bfrag*)&Pl[wave * 1024 + l16 * 64 + ((quad + 4) ^ l7) * 8];
#pragma unroll
    for (int dt = 0; dt < 8; ++dt) {
      bfrag vf0 = *(const bfrag*)&Vl[(dt * 16 + l16) * 64 + ((quad)     ^ l7) * 8];
      bfrag vf1 = *(const bfrag*)&Vl[(dt * 16 + l16) * 64 + ((quad + 4) ^ l7) * 8];
      o[dt] = __builtin_amdgcn_mfma_f32_16x16x32_bf16(pf0, vf0, o[dt], 0, 0, 0);
      o[dt] = __builtin_amdgcn_mfma_f32_16x16x32_bf16(pf1, vf1, o[dt], 0, 0, 0);
    }
  }

  float linv[4];
#pragma unroll
  for (int r = 0; r < 4; ++r) linv[r] = 1.0f / l_r[r];
#pragma unroll
  for (int dt = 0; dt < 8; ++dt) {
#pragma unroll
    for (int r = 0; r < 4; ++r) {
      int s = qb + wave * 16 + quad * 4 + r;
      attn[(size_t)s * DM + h * HD + dt * 16 + l16] = f2bf(o[dt][r] * linv[r]);
    }
  }
}

// ---------------- launch ----------------
extern "C" void kernel_launch(void* const* d_in, const int* in_sizes, int n_in,
                              void* d_out, int out_size, void* d_ws, size_t ws_size,
                              hipStream_t stream) {
  const float* image = (const float*)d_in[0];
  const float* text = (const float*)d_in[1];
  const float* img_cos = (const float*)d_in[2];
  const float* img_sin = (const float*)d_in[3];
  const float* txt_cos = (const float*)d_in[4];
  const float* txt_sin = (const float*)d_in[5];
  const float* Wqkv = (const float*)d_in[6];
  const float* bqkv = (const float*)d_in[7];
  const float* Wadd = (const float*)d_in[8];
  const float* badd = (const float*)d_in[9];
  const float* gq = (const float*)d_in[10];
  const float* gk = (const float*)d_in[11];
  const float* gaq = (const float*)d_in[12];
  const float* gak = (const float*)d_in[13];
  const float* Wout = (const float*)d_in[14];
  const float* bout = (const float*)d_in[15];
  const float* Waddout = (const float*)d_in[16];
  const float* baddout = (const float*)d_in[17];

  char* ws = (char*)d_ws;
  size_t off = 0;
  // x_bf: [SALL][DM] bf16, txt rows 0-255 then img rows (matches attention s-order).
  // Dead after QKV GEMM; attn (same size) aliases it.
  unsigned short* x_bf = (unsigned short*)(ws + off); off += (size_t)SALL * DM * 2;        // 14.2 MB
  unsigned short* attn = x_bf;  // alias: [SALL][DM] bf16, written by flash only
  unsigned short* Wqkv_t = (unsigned short*)(ws + off); off += (size_t)DM3 * DM * 2;       // 56.6 MB
  unsigned short* Wadd_t = (unsigned short*)(ws + off); off += (size_t)DM3 * DM * 2;       // 56.6 MB
  unsigned short* Wout_t = (unsigned short*)(ws + off); off += (size_t)DM * DM * 2;        // 18.9 MB
  unsigned short* Waddout_t = (unsigned short*)(ws + off); off += (size_t)DM * DM * 2;     // 18.9 MB
  float* qkvf = (float*)(ws + off); off += (size_t)2 * NH * SALL * HD * 4;                 // 56.6 MB
  unsigned short* Qb = (unsigned short*)(ws + off); off += (size_t)NH * SALL * HD * 2;     // 14.2 MB
  unsigned short* Kb = (unsigned short*)(ws + off); off += (size_t)NH * SALL * HD * 2;     // 14.2 MB
  unsigned short* Vtb = (unsigned short*)(ws + off); off += (size_t)NH * HD * SALL * 2;    // 14.2 MB
  if (off > ws_size) return;

  cast_kernel<<<STXT * DM / 2048, 256, 0, stream>>>(text, x_bf);
  cast_kernel<<<SIMG * DM / 2048, 256, 0, stream>>>(image, x_bf + (size_t)STXT * DM);
  transpose_cast_kernel<<<dim3(DM3 / 64, DM / 64), 256, 0, stream>>>(Wqkv, Wqkv_t, DM, DM3);
  transpose_cast_kernel<<<dim3(DM3 / 64, DM / 64), 256, 0, stream>>>(Wadd, Wadd_t, DM, DM3);
  transpose_cast_kernel<<<dim3(DM / 64, DM / 64), 256, 0, stream>>>(Wout, Wout_t, DM, DM);
  transpose_cast_kernel<<<dim3(DM / 64, DM / 64), 256, 0, stream>>>(Waddout, Waddout_t, DM, DM);

  // merged QKV projection: blocks with m0 < 256 = txt (Wadd/badd), rest = img (Wqkv/bqkv)
  gemm128<<<dim3((DM3 / 128) * (SALL / 128)), 256, 0, stream>>>(
      x_bf, Wadd_t, Wqkv_t, badd, bqkv, DM3, DM, DM3 / 128, 0, qkvf, Vtb, nullptr, nullptr);

  norm_rope_kernel<<<2 * NH * SALL / 4, 256, 0, stream>>>(qkvf, gq, gk, gaq, gak, img_cos,
                                                          img_sin, txt_cos, txt_sin, Qb, Kb);

  flash_kernel<<<dim3(SALL / 64 * NH), 256, 0, stream>>>(Qb, Kb, Vtb, attn);

  // merged output projection: txt rows -> d_out tail (Waddout), img rows -> d_out head (Wout)
  gemm128<<<dim3((DM / 128) * (SALL / 128)), 256, 0, stream>>>(
      attn, Waddout_t, Wout_t, baddout, bout, DM, DM, DM / 128, 2, nullptr, nullptr,
      (float*)d_out + (size_t)SIMG * DM, (float*)d_out);
}